// Round 9
// baseline (1388.885 us; speedup 1.0000x reference)
//
#include <hip/hip_runtime.h>

using u8 = unsigned char;

// ---------------- mask init: m = (maskraw == 0) ----------------
__global__ void mask_init_k(const int* __restrict__ mr, u8* __restrict__ m, int N) {
    int i = blockIdx.x * blockDim.x + threadIdx.x;
    if (i < N) m[i] = (mr[i] == 0) ? 1 : 0;
}

// ---------------- mask pool 2x2x2 (logical OR), full batch ----------------
template <int SO>
__global__ void pool_k(const u8* __restrict__ mi, u8* __restrict__ mo) {
    const int N = 128 * SO * SO * SO;
    constexpr int SI = 2 * SO;
    int v = blockIdx.x * blockDim.x + threadIdx.x;
    if (v >= N) return;
    int t = v;
    int x = t % SO; t /= SO;
    int y = t % SO; t /= SO;
    int z = t % SO;
    int n = t / SO;
    u8 m = 0;
    for (int kd = 0; kd < 2; kd++)
        for (int kh = 0; kh < 2; kh++)
            for (int kw = 0; kw < 2; kw++)
                m |= mi[((n * SI + 2 * z + kd) * SI + 2 * y + kh) * SI + 2 * x + kw];
    mo[v] = m;
}

// ================= 32^3 LDS-tiled kernels (0 bank conflicts) =================

// ---------------- prepare conv 1->4, k=3 (input masked at stage-in) ----------------
__global__ void prep4t_k(const float* __restrict__ vox, const u8* __restrict__ m,
                         const float* __restrict__ wp, float* __restrict__ out) {
    __shared__ float til[6 * 10 * 35];   // 8.4 KB
    int bid = blockIdx.x;
    int y0 = (bid & 3) << 3, z0 = ((bid >> 2) & 7) << 2, n = bid >> 5;
    for (int t = threadIdx.x; t < 6 * 10 * 35; t += 256) {
        int x_ = t % 35;
        int rr = t / 35;
        int yy = rr % 10, zz = rr / 10;
        int gx = x_ - 1, gy = y0 + yy - 1, gz = z0 + zz - 1;
        float v = 0.f;
        if ((unsigned)gx < 32u && (unsigned)gy < 32u && (unsigned)gz < 32u) {
            int gi = ((n * 32 + gz) * 32 + gy) * 32 + gx;
            if (m[gi]) v = vox[gi];
        }
        til[t] = v;
    }
    __syncthreads();
    int tx = threadIdx.x;
    int xg = tx & 7, ly = (tx >> 3) & 7, lz = tx >> 6;
    int xb = xg << 2;
    int vbase = ((n * 32 + z0 + lz) * 32 + y0 + ly) * 32 + xb;
    u8 om[4];
#pragma unroll
    for (int j = 0; j < 4; j++) om[j] = m[vbase + j];
    float acc[4][4];
#pragma unroll
    for (int j = 0; j < 4; j++)
#pragma unroll
        for (int co = 0; co < 4; co++) acc[j][co] = 0.f;
    for (int kd = 0; kd < 3; kd++) {
        for (int kh = 0; kh < 3; kh++) {
            const float* rowp = &til[((lz + kd) * 10 + ly + kh) * 35 + xb];
            float col[6];
#pragma unroll
            for (int c = 0; c < 6; c++) col[c] = rowp[c];
            const float* wrow = wp + ((kd * 3 + kh) * 3) * 4;
#pragma unroll
            for (int kw = 0; kw < 3; kw++) {
                const float* wt = wrow + kw * 4;
#pragma unroll
                for (int j = 0; j < 4; j++) {
                    float xv = col[j + kw];
#pragma unroll
                    for (int co = 0; co < 4; co++) acc[j][co] += xv * wt[co];
                }
            }
        }
    }
#pragma unroll
    for (int j = 0; j < 4; j++) {
        float4 o = make_float4(om[j] ? acc[j][0] : 0.f, om[j] ? acc[j][1] : 0.f,
                               om[j] ? acc[j][2] : 0.f, om[j] ? acc[j][3] : 0.f);
        *(float4*)(out + (size_t)(vbase + j) * 4) = o;
    }
}

// ---------------- FUSED: conv k=3 4->4 + BN at stage-in + down k=2 s=2 (4->8ch) ----------------
// Conv result parked in LDS (til reused after barrier); down epilogue computed in-block
// with down_k's exact (kd,kh,kw,ci) tap order -> bit-identical to convbn4t + down_k<4,8,16>.
__global__ void convbndown4t_k(const float* __restrict__ in, const float* __restrict__ w,
                               const u8* __restrict__ mask, const double* __restrict__ params,
                               const float* __restrict__ wd, const u8* __restrict__ m16,
                               float* __restrict__ out16) {
    __shared__ float4 til[6 * 10 * 35];  // 33.6 KB
    float sc[4], sh[4];
#pragma unroll
    for (int c = 0; c < 4; c++) { sc[c] = (float)params[c]; sh[c] = (float)params[4 + c]; }
    int bid = blockIdx.x;
    int y0 = (bid & 3) << 3, z0 = ((bid >> 2) & 7) << 2, n = bid >> 5;
    for (int t = threadIdx.x; t < 6 * 10 * 35; t += 256) {
        int x_ = t % 35;
        int rr = t / 35;
        int yy = rr % 10, zz = rr / 10;
        int gx = x_ - 1, gy = y0 + yy - 1, gz = z0 + zz - 1;
        float4 v = make_float4(0.f, 0.f, 0.f, 0.f);
        if ((unsigned)gx < 32u && (unsigned)gy < 32u && (unsigned)gz < 32u) {
            int gi = ((n * 32 + gz) * 32 + gy) * 32 + gx;
            if (mask[gi]) {
                float4 r = *(const float4*)(in + (size_t)gi * 4);
                v.x = fmaxf(r.x * sc[0] + sh[0], 0.f);
                v.y = fmaxf(r.y * sc[1] + sh[1], 0.f);
                v.z = fmaxf(r.z * sc[2] + sh[2], 0.f);
                v.w = fmaxf(r.w * sc[3] + sh[3], 0.f);
            }
        }
        til[t] = v;
    }
    __syncthreads();
    int tx = threadIdx.x;
    int xg = tx & 7, ly = (tx >> 3) & 7, lz = tx >> 6;
    int xb = xg << 2;
    int vbase = ((n * 32 + z0 + lz) * 32 + y0 + ly) * 32 + xb;
    u8 om[4];
#pragma unroll
    for (int j = 0; j < 4; j++) om[j] = mask[vbase + j];
    float acc[4][4];
#pragma unroll
    for (int j = 0; j < 4; j++)
#pragma unroll
        for (int co = 0; co < 4; co++) acc[j][co] = 0.f;
    for (int kd = 0; kd < 3; kd++) {
        for (int kh = 0; kh < 3; kh++) {
            const float4* rowp = &til[((lz + kd) * 10 + ly + kh) * 35 + xb];
            float col[6][4];
#pragma unroll
            for (int c = 0; c < 6; c++) {
                float4 t4 = rowp[c];
                col[c][0] = t4.x; col[c][1] = t4.y; col[c][2] = t4.z; col[c][3] = t4.w;
            }
            const float* wrow = w + ((kd * 3 + kh) * 3) * 16;
#pragma unroll
            for (int kw = 0; kw < 3; kw++) {
                const float* wt = wrow + kw * 16;
#pragma unroll
                for (int j = 0; j < 4; j++) {
#pragma unroll
                    for (int ci = 0; ci < 4; ci++) {
                        float xv = col[j + kw][ci];
#pragma unroll
                        for (int co = 0; co < 4; co++) acc[j][co] += xv * wt[ci * 4 + co];
                    }
                }
            }
        }
    }
    __syncthreads();   // all conv reads of til done; reuse til for gated results
    int ridx = (lz * 8 + ly) * 32 + xb;
#pragma unroll
    for (int j = 0; j < 4; j++) {
        til[ridx + j] = make_float4(om[j] ? acc[j][0] : 0.f, om[j] ? acc[j][1] : 0.f,
                                    om[j] ? acc[j][2] : 0.f, om[j] ? acc[j][3] : 0.f);
    }
    __syncthreads();
    if (tx < 128) {
        int ox = tx & 15, oy = (tx >> 4) & 3, oz = tx >> 6;
        int y16 = (y0 >> 1) + oy, z16 = (z0 >> 1) + oz;
        int v16 = ((n * 16 + z16) * 16 + y16) * 16 + ox;
        float acc8[8];
#pragma unroll
        for (int co = 0; co < 8; co++) acc8[co] = 0.f;
        if (m16[v16]) {
            for (int kd = 0; kd < 2; kd++)
                for (int kh = 0; kh < 2; kh++)
#pragma unroll
                    for (int kw = 0; kw < 2; kw++) {
                        float4 f = til[(((2 * oz + kd) * 8 + 2 * oy + kh) * 32) + 2 * ox + kw];
                        const float* wpk = wd + ((kd * 2 + kh) * 2 + kw) * 32;
                        float xs[4] = {f.x, f.y, f.z, f.w};
#pragma unroll
                        for (int ci = 0; ci < 4; ci++) {
                            float xv = xs[ci];
#pragma unroll
                            for (int co = 0; co < 8; co++) acc8[co] += xv * wpk[ci * 8 + co];
                        }
                    }
        }
        float* op = out16 + (size_t)v16 * 8;
        ((float4*)op)[0] = make_float4(acc8[0], acc8[1], acc8[2], acc8[3]);
        ((float4*)op)[1] = make_float4(acc8[4], acc8[5], acc8[6], acc8[7]);
    }
}

// ---------------- FUSED: upbn(8->4ch, 16^3->32^3) at stage-in + conv k=3 4->4 + sparsify ----------------
// Stage-in computes upbn_k's exact per-voxel value (ci-ascending) from the 16^3 parent.
__global__ void conv3s4tf_k(const float* __restrict__ in16, const float* __restrict__ wu,
                            const float* __restrict__ w, const u8* __restrict__ pmask,
                            u8* __restrict__ nmask, float* __restrict__ out,
                            const double* __restrict__ params) {
    __shared__ float4 til[6 * 10 * 35];  // 33.6 KB
    float sc[8], sh[8];
#pragma unroll
    for (int c = 0; c < 8; c++) { sc[c] = (float)params[c]; sh[c] = (float)params[8 + c]; }
    int bid = blockIdx.x;
    int y0 = (bid & 3) << 3, z0 = ((bid >> 2) & 7) << 2, n = bid >> 5;
    for (int t = threadIdx.x; t < 6 * 10 * 35; t += 256) {
        int x_ = t % 35;
        int rr = t / 35;
        int yy = rr % 10, zz = rr / 10;
        int gx = x_ - 1, gy = y0 + yy - 1, gz = z0 + zz - 1;
        float4 v = make_float4(0.f, 0.f, 0.f, 0.f);
        if ((unsigned)gx < 32u && (unsigned)gy < 32u && (unsigned)gz < 32u) {
            int p16 = ((n * 16 + (gz >> 1)) * 16 + (gy >> 1)) * 16 + (gx >> 1);
            if (pmask[p16]) {
                int tap = ((1 - (gz & 1)) * 2 + (1 - (gy & 1))) * 2 + (1 - (gx & 1));
                const float* ip = in16 + (size_t)p16 * 8;
                const float* wt = wu + tap * 32;
#pragma unroll
                for (int ci = 0; ci < 8; ci++) {
                    float yv = fmaxf(ip[ci] * sc[ci] + sh[ci], 0.f);
                    v.x += yv * wt[ci * 4 + 0];
                    v.y += yv * wt[ci * 4 + 1];
                    v.z += yv * wt[ci * 4 + 2];
                    v.w += yv * wt[ci * 4 + 3];
                }
            }
        }
        til[t] = v;
    }
    __syncthreads();
    int tx = threadIdx.x;
    int xg = tx & 7, ly = (tx >> 3) & 7, lz = tx >> 6;
    int xb = xg << 2;
    int gy = y0 + ly, gz = z0 + lz;
    int vbase = ((n * 32 + gz) * 32 + gy) * 32 + xb;
    int pbase = ((n * 16 + (gz >> 1)) * 16 + (gy >> 1)) * 16 + (xb >> 1);
    u8 pm[4];
    pm[0] = pm[1] = pmask[pbase];
    pm[2] = pm[3] = pmask[pbase + 1];
    double acc0[4];
    float accf[4][4];
#pragma unroll
    for (int j = 0; j < 4; j++) {
        acc0[j] = 0.0;
#pragma unroll
        for (int co = 0; co < 4; co++) accf[j][co] = 0.f;
    }
    for (int kd = 0; kd < 3; kd++) {
        for (int kh = 0; kh < 3; kh++) {
            const float4* rowp = &til[((lz + kd) * 10 + ly + kh) * 35 + xb];
            float col[6][4];
#pragma unroll
            for (int c = 0; c < 6; c++) {
                float4 t4 = rowp[c];
                col[c][0] = t4.x; col[c][1] = t4.y; col[c][2] = t4.z; col[c][3] = t4.w;
            }
            const float* wrow = w + ((kd * 3 + kh) * 3) * 16;
#pragma unroll
            for (int kw = 0; kw < 3; kw++) {
                const float* wt = wrow + kw * 16;
#pragma unroll
                for (int j = 0; j < 4; j++) {
#pragma unroll
                    for (int ci = 0; ci < 4; ci++) {
                        float xv = col[j + kw][ci];
                        acc0[j] += (double)xv * (double)wt[ci * 4 + 0];
#pragma unroll
                        for (int co = 1; co < 4; co++) accf[j][co] += xv * wt[ci * 4 + co];
                    }
                }
            }
        }
    }
    unsigned nm4 = 0;
#pragma unroll
    for (int j = 0; j < 4; j++) {
        u8 nm = (pm[j] && (acc0[j] > 0.0)) ? 1 : 0;
        nm4 |= ((unsigned)nm) << (8 * j);
        float4 o = make_float4(nm ? (float)acc0[j] : 0.f, nm ? accf[j][1] : 0.f,
                               nm ? accf[j][2] : 0.f, nm ? accf[j][3] : 0.f);
        *(float4*)(out + (size_t)(vbase + j) * 4) = o;
    }
    *(unsigned*)(nmask + vbase) = nm4;
}

// ---------------- plain conv 4->4, k=4 pad(1,2) ----------------
__global__ void conv4x4t_k(const float* __restrict__ in, const float* __restrict__ w,
                           const u8* __restrict__ outmask, float* __restrict__ out) {
    __shared__ float4 til[7 * 11 * 35];  // 43.1 KB
    int bid = blockIdx.x;
    int y0 = (bid & 3) << 3, z0 = ((bid >> 2) & 7) << 2, n = bid >> 5;
    for (int t = threadIdx.x; t < 7 * 11 * 35; t += 256) {
        int x_ = t % 35;
        int rr = t / 35;
        int yy = rr % 11, zz = rr / 11;
        int gx = x_ - 1, gy = y0 + yy - 1, gz = z0 + zz - 1;
        float4 v = make_float4(0.f, 0.f, 0.f, 0.f);
        if ((unsigned)gx < 32u && (unsigned)gy < 32u && (unsigned)gz < 32u)
            v = *(const float4*)(in + (size_t)(((n * 32 + gz) * 32 + gy) * 32 + gx) * 4);
        til[t] = v;
    }
    __syncthreads();
    int tx = threadIdx.x;
    int xg = tx & 7, ly = (tx >> 3) & 7, lz = tx >> 6;
    int xb = xg << 2;
    int vbase = ((n * 32 + z0 + lz) * 32 + y0 + ly) * 32 + xb;
    u8 om[4];
#pragma unroll
    for (int j = 0; j < 4; j++) om[j] = outmask[vbase + j];
    float acc[4][4];
#pragma unroll
    for (int j = 0; j < 4; j++)
#pragma unroll
        for (int co = 0; co < 4; co++) acc[j][co] = 0.f;
    for (int kd = 0; kd < 4; kd++) {
        for (int kh = 0; kh < 4; kh++) {
            const float4* rowp = &til[((lz + kd) * 11 + ly + kh) * 35 + xb];
            float col[7][4];
#pragma unroll
            for (int c = 0; c < 7; c++) {
                float4 t4 = rowp[c];
                col[c][0] = t4.x; col[c][1] = t4.y; col[c][2] = t4.z; col[c][3] = t4.w;
            }
            const float* wrow = w + ((kd * 4 + kh) * 4) * 16;
#pragma unroll
            for (int kw = 0; kw < 4; kw++) {
                const float* wt = wrow + kw * 16;
#pragma unroll
                for (int j = 0; j < 4; j++) {
#pragma unroll
                    for (int ci = 0; ci < 4; ci++) {
                        float xv = col[j + kw][ci];
#pragma unroll
                        for (int co = 0; co < 4; co++) acc[j][co] += xv * wt[ci * 4 + co];
                    }
                }
            }
        }
    }
#pragma unroll
    for (int j = 0; j < 4; j++) {
        float4 o = make_float4(om[j] ? acc[j][0] : 0.f, om[j] ? acc[j][1] : 0.f,
                               om[j] ? acc[j][2] : 0.f, om[j] ? acc[j][3] : 0.f);
        *(float4*)(out + (size_t)(vbase + j) * 4) = o;
    }
}

// ---------------- final output conv k=3, 4->1 ----------------
__global__ void outconv4t_k(const float* __restrict__ in, const float* __restrict__ w,
                            const u8* __restrict__ mask, float* __restrict__ out) {
    __shared__ float4 til[6 * 10 * 35];  // 33.6 KB
    int bid = blockIdx.x;
    int y0 = (bid & 3) << 3, z0 = ((bid >> 2) & 7) << 2, n = bid >> 5;
    for (int t = threadIdx.x; t < 6 * 10 * 35; t += 256) {
        int x_ = t % 35;
        int rr = t / 35;
        int yy = rr % 10, zz = rr / 10;
        int gx = x_ - 1, gy = y0 + yy - 1, gz = z0 + zz - 1;
        float4 v = make_float4(0.f, 0.f, 0.f, 0.f);
        if ((unsigned)gx < 32u && (unsigned)gy < 32u && (unsigned)gz < 32u)
            v = *(const float4*)(in + (size_t)(((n * 32 + gz) * 32 + gy) * 32 + gx) * 4);
        til[t] = v;
    }
    __syncthreads();
    int tx = threadIdx.x;
    int xg = tx & 7, ly = (tx >> 3) & 7, lz = tx >> 6;
    int xb = xg << 2;
    int vbase = ((n * 32 + z0 + lz) * 32 + y0 + ly) * 32 + xb;
    u8 om[4];
#pragma unroll
    for (int j = 0; j < 4; j++) om[j] = mask[vbase + j];
    float acc[4] = {0.f, 0.f, 0.f, 0.f};
    for (int kd = 0; kd < 3; kd++) {
        for (int kh = 0; kh < 3; kh++) {
            const float4* rowp = &til[((lz + kd) * 10 + ly + kh) * 35 + xb];
            float col[6][4];
#pragma unroll
            for (int c = 0; c < 6; c++) {
                float4 t4 = rowp[c];
                col[c][0] = t4.x; col[c][1] = t4.y; col[c][2] = t4.z; col[c][3] = t4.w;
            }
            const float* wrow = w + ((kd * 3 + kh) * 3) * 4;
#pragma unroll
            for (int kw = 0; kw < 3; kw++) {
                const float* wt = wrow + kw * 4;
#pragma unroll
                for (int j = 0; j < 4; j++) {
#pragma unroll
                    for (int ci = 0; ci < 4; ci++) acc[j] += col[j + kw][ci] * wt[ci];
                }
            }
        }
    }
    float4 o = make_float4(om[0] ? acc[0] : 0.f, om[1] ? acc[1] : 0.f,
                           om[2] ? acc[2] : 0.f, om[3] ? acc[3] : 0.f);
    *(float4*)(out + vbase) = o;
}

// ================= 16^3 LDS-tiled kernels (8ch = 2 quads), XPT=2 =================

// ---------------- FUSED: conv k=3 8->8 + BN at stage-in + down k=2 s=2 (8->16ch) ----------------
__global__ void convbndown16t_k(const float* __restrict__ in, const float* __restrict__ w,
                                const u8* __restrict__ mask, const double* __restrict__ params,
                                const float* __restrict__ wd, const u8* __restrict__ m8,
                                float* __restrict__ out8) {
    __shared__ float4 til[2][1140];   // 36.5 KB
    __shared__ float wl[1728];        // 6.9 KB
    float sc[8], sh[8];
#pragma unroll
    for (int c = 0; c < 8; c++) { sc[c] = (float)params[c]; sh[c] = (float)params[8 + c]; }
    int bid = blockIdx.x;
    int y0 = (bid & 1) << 3, z0 = ((bid >> 1) & 3) << 2, n = bid >> 3;
    for (int t = threadIdx.x; t < 1728; t += 256) wl[t] = w[t];
    for (int t = threadIdx.x; t < 1140; t += 256) {
        int x_ = t % 19;
        int rr = t / 19;
        int yy = rr % 10, zz = rr / 10;
        int gx = x_ - 1, gy = y0 + yy - 1, gz = z0 + zz - 1;
        float v[8];
#pragma unroll
        for (int c = 0; c < 8; c++) v[c] = 0.f;
        if ((unsigned)gx < 16u && (unsigned)gy < 16u && (unsigned)gz < 16u) {
            int gi = ((n * 16 + gz) * 16 + gy) * 16 + gx;
            if (mask[gi]) {
                const float* ip = in + (size_t)gi * 8;
#pragma unroll
                for (int c = 0; c < 8; c++) v[c] = fmaxf(ip[c] * sc[c] + sh[c], 0.f);
            }
        }
        til[0][t] = make_float4(v[0], v[1], v[2], v[3]);
        til[1][t] = make_float4(v[4], v[5], v[6], v[7]);
    }
    __syncthreads();
    int xg = threadIdx.x & 7, ly = (threadIdx.x >> 3) & 7, lz = threadIdx.x >> 6;
    int xb = xg << 1;
    int vbase = ((n * 16 + z0 + lz) * 16 + y0 + ly) * 16 + xb;
    u8 om[2] = {mask[vbase], mask[vbase + 1]};
    float acc[2][8];
#pragma unroll
    for (int j = 0; j < 2; j++)
#pragma unroll
        for (int co = 0; co < 8; co++) acc[j][co] = 0.f;
    for (int kd = 0; kd < 3; kd++) {
        for (int kh = 0; kh < 3; kh++) {
            int rbase = ((lz + kd) * 10 + ly + kh) * 19 + xb;
            float col[4][8];
#pragma unroll
            for (int c = 0; c < 4; c++) {
                float4 a = til[0][rbase + c], b = til[1][rbase + c];
                col[c][0] = a.x; col[c][1] = a.y; col[c][2] = a.z; col[c][3] = a.w;
                col[c][4] = b.x; col[c][5] = b.y; col[c][6] = b.z; col[c][7] = b.w;
            }
            const float* wrow = wl + ((kd * 3 + kh) * 3) * 64;
#pragma unroll
            for (int kw = 0; kw < 3; kw++) {
                const float* wt = wrow + kw * 64;
#pragma unroll
                for (int j = 0; j < 2; j++) {
#pragma unroll
                    for (int ci = 0; ci < 8; ci++) {
                        float xv = col[j + kw][ci];
#pragma unroll
                        for (int co = 0; co < 8; co++) acc[j][co] += xv * wt[ci * 8 + co];
                    }
                }
            }
        }
    }
    __syncthreads();   // conv reads done; reuse til for gated results (512 voxels)
    int ridx = (lz * 8 + ly) * 16 + xb;
#pragma unroll
    for (int j = 0; j < 2; j++) {
        float g0 = om[j] ? acc[j][0] : 0.f, g1 = om[j] ? acc[j][1] : 0.f;
        float g2 = om[j] ? acc[j][2] : 0.f, g3 = om[j] ? acc[j][3] : 0.f;
        float g4 = om[j] ? acc[j][4] : 0.f, g5 = om[j] ? acc[j][5] : 0.f;
        float g6 = om[j] ? acc[j][6] : 0.f, g7 = om[j] ? acc[j][7] : 0.f;
        til[0][ridx + j] = make_float4(g0, g1, g2, g3);
        til[1][ridx + j] = make_float4(g4, g5, g6, g7);
    }
    __syncthreads();
    int tx = threadIdx.x;
    if (tx < 128) {
        int ox = tx & 7, oy = (tx >> 3) & 3, oz = (tx >> 5) & 1, cq2 = tx >> 6;  // co half
        int y8 = (y0 >> 1) + oy, z8 = (z0 >> 1) + oz;
        int v8 = ((n * 8 + z8) * 8 + y8) * 8 + ox;
        float acc16[8];
#pragma unroll
        for (int co = 0; co < 8; co++) acc16[co] = 0.f;
        if (m8[v8]) {
            for (int kd = 0; kd < 2; kd++)
                for (int kh = 0; kh < 2; kh++)
#pragma unroll
                    for (int kw = 0; kw < 2; kw++) {
                        int si = (((2 * oz + kd) * 8 + 2 * oy + kh) * 16) + 2 * ox + kw;
                        float4 a = til[0][si], b = til[1][si];
                        float xs[8] = {a.x, a.y, a.z, a.w, b.x, b.y, b.z, b.w};
                        const float* wpk = wd + ((kd * 2 + kh) * 2 + kw) * 128 + cq2 * 8;
#pragma unroll
                        for (int ci = 0; ci < 8; ci++) {
                            float xv = xs[ci];
#pragma unroll
                            for (int co = 0; co < 8; co++) acc16[co] += xv * wpk[ci * 16 + co];
                        }
                    }
        }
        float* op = out8 + (size_t)v8 * 16 + cq2 * 8;
        ((float4*)op)[0] = make_float4(acc16[0], acc16[1], acc16[2], acc16[3]);
        ((float4*)op)[1] = make_float4(acc16[4], acc16[5], acc16[6], acc16[7]);
    }
}

// ---------------- FUSED: upbn(16->8ch, 8^3->16^3) at stage-in + conv k=3 8->8 + sparsify ----------------
__global__ void conv3s16tf_k(const float* __restrict__ in8, const float* __restrict__ wu,
                             const float* __restrict__ w, const u8* __restrict__ pmask,
                             u8* __restrict__ nmask, float* __restrict__ out,
                             const double* __restrict__ params, double delta) {
    __shared__ float4 til[2][1140];   // 36.5 KB
    __shared__ float wl[1728];        // 6.9 KB
    float sc[16], sh[16];
#pragma unroll
    for (int c = 0; c < 16; c++) { sc[c] = (float)params[c]; sh[c] = (float)params[16 + c]; }
    int bid = blockIdx.x;
    int y0 = (bid & 1) << 3, z0 = ((bid >> 1) & 3) << 2, n = bid >> 3;
    for (int t = threadIdx.x; t < 1728; t += 256) wl[t] = w[t];
    for (int t = threadIdx.x; t < 1140; t += 256) {
        int x_ = t % 19;
        int rr = t / 19;
        int yy = rr % 10, zz = rr / 10;
        int gx = x_ - 1, gy = y0 + yy - 1, gz = z0 + zz - 1;
        float v[8];
#pragma unroll
        for (int c = 0; c < 8; c++) v[c] = 0.f;
        if ((unsigned)gx < 16u && (unsigned)gy < 16u && (unsigned)gz < 16u) {
            int p8 = ((n * 8 + (gz >> 1)) * 8 + (gy >> 1)) * 8 + (gx >> 1);
            if (pmask[p8]) {
                int tap = ((1 - (gz & 1)) * 2 + (1 - (gy & 1))) * 2 + (1 - (gx & 1));
                const float* ip = in8 + (size_t)p8 * 16;
                const float* wt = wu + tap * 128;
#pragma unroll
                for (int ci = 0; ci < 16; ci++) {
                    float yv = fmaxf(ip[ci] * sc[ci] + sh[ci], 0.f);
#pragma unroll
                    for (int co = 0; co < 8; co++) v[co] += yv * wt[ci * 8 + co];
                }
            }
        }
        til[0][t] = make_float4(v[0], v[1], v[2], v[3]);
        til[1][t] = make_float4(v[4], v[5], v[6], v[7]);
    }
    __syncthreads();
    int xg = threadIdx.x & 7, ly = (threadIdx.x >> 3) & 7, lz = threadIdx.x >> 6;
    int xb = xg << 1;
    int gy = y0 + ly, gz = z0 + lz;
    int vbase = ((n * 16 + gz) * 16 + gy) * 16 + xb;
    u8 pm = pmask[((n * 8 + (gz >> 1)) * 8 + (gy >> 1)) * 8 + (xb >> 1)];
    double acc0[2], asum[2];
    float accf[2][8];
#pragma unroll
    for (int j = 0; j < 2; j++) {
        acc0[j] = 0.0; asum[j] = 0.0;
#pragma unroll
        for (int co = 0; co < 8; co++) accf[j][co] = 0.f;
    }
    for (int kd = 0; kd < 3; kd++) {
        for (int kh = 0; kh < 3; kh++) {
            int rbase = ((lz + kd) * 10 + ly + kh) * 19 + xb;
            float col[4][8];
#pragma unroll
            for (int c = 0; c < 4; c++) {
                float4 a = til[0][rbase + c], b = til[1][rbase + c];
                col[c][0] = a.x; col[c][1] = a.y; col[c][2] = a.z; col[c][3] = a.w;
                col[c][4] = b.x; col[c][5] = b.y; col[c][6] = b.z; col[c][7] = b.w;
            }
            const float* wrow = wl + ((kd * 3 + kh) * 3) * 64;
#pragma unroll
            for (int kw = 0; kw < 3; kw++) {
                const float* wt = wrow + kw * 64;
#pragma unroll
                for (int j = 0; j < 2; j++) {
#pragma unroll
                    for (int ci = 0; ci < 8; ci++) {
                        float xv = col[j + kw][ci];
                        double term = (double)xv * (double)wt[ci * 8 + 0];
                        acc0[j] += term;
                        asum[j] += fabs(term);
#pragma unroll
                        for (int co = 1; co < 8; co++) accf[j][co] += xv * wt[ci * 8 + co];
                    }
                }
            }
        }
    }
    unsigned short nm2 = 0;
#pragma unroll
    for (int j = 0; j < 2; j++) {
        u8 nm = (pm && (acc0[j] > -delta * asum[j])) ? 1 : 0;
        nm2 |= ((unsigned short)nm) << (8 * j);
        float* op = out + (size_t)(vbase + j) * 8;
        float4 o0 = make_float4(nm ? (float)acc0[j] : 0.f, nm ? accf[j][1] : 0.f,
                                nm ? accf[j][2] : 0.f, nm ? accf[j][3] : 0.f);
        float4 o1 = make_float4(nm ? accf[j][4] : 0.f, nm ? accf[j][5] : 0.f,
                                nm ? accf[j][6] : 0.f, nm ? accf[j][7] : 0.f);
        ((float4*)op)[0] = o0;
        ((float4*)op)[1] = o1;
    }
    *(unsigned short*)(nmask + vbase) = nm2;
}

// ---------------- plain conv k=4 pad(1,2), 8->8; weights staged per-kd slab ----------------
__global__ void conv416t_k(const float* __restrict__ in, const float* __restrict__ w,
                           const u8* __restrict__ outmask, float* __restrict__ out) {
    __shared__ float4 til[2][1463];   // 46.8 KB
    __shared__ float wl[1024];        // 4 KB
    int bid = blockIdx.x;
    int y0 = (bid & 1) << 3, z0 = ((bid >> 1) & 3) << 2, n = bid >> 3;
    for (int t = threadIdx.x; t < 1463; t += 256) {
        int x_ = t % 19;
        int rr = t / 19;
        int yy = rr % 11, zz = rr / 11;
        int gx = x_ - 1, gy = y0 + yy - 1, gz = z0 + zz - 1;
        float4 a = make_float4(0.f, 0.f, 0.f, 0.f), b = a;
        if ((unsigned)gx < 16u && (unsigned)gy < 16u && (unsigned)gz < 16u) {
            const float4* ip = (const float4*)(in + (size_t)(((n * 16 + gz) * 16 + gy) * 16 + gx) * 8);
            a = ip[0]; b = ip[1];
        }
        til[0][t] = a;
        til[1][t] = b;
    }
    int xg = threadIdx.x & 7, ly = (threadIdx.x >> 3) & 7, lz = threadIdx.x >> 6;
    int xb = xg << 1;
    int vbase = ((n * 16 + z0 + lz) * 16 + y0 + ly) * 16 + xb;
    u8 om[2] = {outmask[vbase], outmask[vbase + 1]};
    float acc[2][8];
#pragma unroll
    for (int j = 0; j < 2; j++)
#pragma unroll
        for (int co = 0; co < 8; co++) acc[j][co] = 0.f;
    for (int kd = 0; kd < 4; kd++) {
        __syncthreads();
        for (int t = threadIdx.x; t < 1024; t += 256) wl[t] = w[kd * 1024 + t];
        __syncthreads();
        for (int kh = 0; kh < 4; kh++) {
            int rbase = ((lz + kd) * 11 + ly + kh) * 19 + xb;
            float col[5][8];
#pragma unroll
            for (int c = 0; c < 5; c++) {
                float4 a = til[0][rbase + c], b = til[1][rbase + c];
                col[c][0] = a.x; col[c][1] = a.y; col[c][2] = a.z; col[c][3] = a.w;
                col[c][4] = b.x; col[c][5] = b.y; col[c][6] = b.z; col[c][7] = b.w;
            }
            const float* wrow = wl + (kh * 4) * 64;
#pragma unroll
            for (int kw = 0; kw < 4; kw++) {
                const float* wt = wrow + kw * 64;
#pragma unroll
                for (int j = 0; j < 2; j++) {
#pragma unroll
                    for (int ci = 0; ci < 8; ci++) {
                        float xv = col[j + kw][ci];
#pragma unroll
                        for (int co = 0; co < 8; co++) acc[j][co] += xv * wt[ci * 8 + co];
                    }
                }
            }
        }
    }
#pragma unroll
    for (int j = 0; j < 2; j++) {
        float* op = out + (size_t)(vbase + j) * 8;
        float4 o0 = make_float4(om[j] ? acc[j][0] : 0.f, om[j] ? acc[j][1] : 0.f,
                                om[j] ? acc[j][2] : 0.f, om[j] ? acc[j][3] : 0.f);
        float4 o1 = make_float4(om[j] ? acc[j][4] : 0.f, om[j] ? acc[j][5] : 0.f,
                                om[j] ? acc[j][6] : 0.f, om[j] ? acc[j][7] : 0.f);
        ((float4*)op)[0] = o0;
        ((float4*)op)[1] = o1;
    }
}

// ================= 8^3 LDS-tiled kernels (16ch), quad-split + weights-in-LDS =================

// ---------------- conv k=3, 16->16, BN(affine+ReLU+mask) at stage-in ----------------
__global__ void convbn8_k(const float* __restrict__ in, const float* __restrict__ w,
                          const u8* __restrict__ mask, const double* __restrict__ params,
                          float* __restrict__ out) {
    __shared__ float4 til[4][330];   // 21.1 KB
    __shared__ float wl[27 * 256];   // 27 KB
    float sc[16], sh[16];
#pragma unroll
    for (int c = 0; c < 16; c++) { sc[c] = (float)params[c]; sh[c] = (float)params[16 + c]; }
    int z = blockIdx.x & 7, n = blockIdx.x >> 3;
    for (int t = threadIdx.x; t < 27 * 256; t += 256) wl[t] = w[t];
    for (int t = threadIdx.x; t < 300; t += 256) {
        int xx = t % 10;
        int rr = t / 10;
        int yy = rr % 10, zz = rr / 10;
        int gx = xx - 1, gy = yy - 1, gz = z + zz - 1;
        float v[16];
#pragma unroll
        for (int c = 0; c < 16; c++) v[c] = 0.f;
        if ((unsigned)gx < 8u && (unsigned)gy < 8u && (unsigned)gz < 8u) {
            int gi = ((n * 8 + gz) * 8 + gy) * 8 + gx;
            if (mask[gi]) {
                const float* ip = in + (size_t)gi * 16;
#pragma unroll
                for (int c = 0; c < 16; c++) v[c] = fmaxf(ip[c] * sc[c] + sh[c], 0.f);
            }
        }
        int s = (zz * 10 + yy) * 11 + xx;
#pragma unroll
        for (int q = 0; q < 4; q++)
            til[q][s] = make_float4(v[4 * q], v[4 * q + 1], v[4 * q + 2], v[4 * q + 3]);
    }
    __syncthreads();
    int x = threadIdx.x & 7, y = (threadIdx.x >> 3) & 7, cq = threadIdx.x >> 6;
    int v = ((n * 8 + z) * 8 + y) * 8 + x;
    u8 om = mask[v];
    float acc[4] = {0.f, 0.f, 0.f, 0.f};
    for (int kd = 0; kd < 3; kd++) {
        for (int kh = 0; kh < 3; kh++) {
            int rbase = (kd * 10 + y + kh) * 11 + x;
            const float* wrow = wl + ((kd * 3 + kh) * 3) * 256;
#pragma unroll
            for (int kw = 0; kw < 3; kw++) {
                int s = rbase + kw;
                float4 q0 = til[0][s], q1 = til[1][s], q2 = til[2][s], q3 = til[3][s];
                float xs[16] = {q0.x, q0.y, q0.z, q0.w, q1.x, q1.y, q1.z, q1.w,
                                q2.x, q2.y, q2.z, q2.w, q3.x, q3.y, q3.z, q3.w};
                const float* wt = wrow + kw * 256 + cq * 4;
#pragma unroll
                for (int ci = 0; ci < 16; ci++) {
                    float xv = xs[ci];
                    float4 w4 = *(const float4*)(wt + ci * 16);
                    acc[0] += xv * w4.x; acc[1] += xv * w4.y;
                    acc[2] += xv * w4.z; acc[3] += xv * w4.w;
                }
            }
        }
    }
    float4 o = make_float4(om ? acc[0] : 0.f, om ? acc[1] : 0.f,
                           om ? acc[2] : 0.f, om ? acc[3] : 0.f);
    *(float4*)(out + (size_t)v * 16 + cq * 4) = o;
}

// ---------------- FUSED: upbn(32->16ch, 4^3->8^3) at stage-in + conv k=3 16->16 + sparsify ----------------
__global__ void conv3s8f_k(const float* __restrict__ in4, const float* __restrict__ wu,
                           const float* __restrict__ w, const u8* __restrict__ pmask,
                           u8* __restrict__ nmask, float* __restrict__ out,
                           const double* __restrict__ params, double delta) {
    __shared__ float4 til[4][330];   // 21.1 KB
    __shared__ float wl[27 * 256];   // 27 KB
    __shared__ u8 nmsh[64];
    float sc[32], sh[32];
#pragma unroll
    for (int c = 0; c < 32; c++) { sc[c] = (float)params[c]; sh[c] = (float)params[32 + c]; }
    int z = blockIdx.x & 7, n = blockIdx.x >> 3;
    for (int t = threadIdx.x; t < 27 * 256; t += 256) wl[t] = w[t];
    for (int t = threadIdx.x; t < 300; t += 256) {
        int xx = t % 10;
        int rr = t / 10;
        int yy = rr % 10, zz = rr / 10;
        int gx = xx - 1, gy = yy - 1, gz = z + zz - 1;
        float v[16];
#pragma unroll
        for (int c = 0; c < 16; c++) v[c] = 0.f;
        if ((unsigned)gx < 8u && (unsigned)gy < 8u && (unsigned)gz < 8u) {
            int p4 = ((n * 4 + (gz >> 1)) * 4 + (gy >> 1)) * 4 + (gx >> 1);
            if (pmask[p4]) {
                int tap = ((1 - (gz & 1)) * 2 + (1 - (gy & 1))) * 2 + (1 - (gx & 1));
                const float* ip = in4 + (size_t)p4 * 32;
                const float* wt = wu + tap * 512;
#pragma unroll
                for (int ci = 0; ci < 32; ci++) {
                    float yv = fmaxf(ip[ci] * sc[ci] + sh[ci], 0.f);
#pragma unroll
                    for (int co = 0; co < 16; co++) v[co] += yv * wt[ci * 16 + co];
                }
            }
        }
        int s = (zz * 10 + yy) * 11 + xx;
#pragma unroll
        for (int q = 0; q < 4; q++)
            til[q][s] = make_float4(v[4 * q], v[4 * q + 1], v[4 * q + 2], v[4 * q + 3]);
    }
    __syncthreads();
    int x = threadIdx.x & 7, y = (threadIdx.x >> 3) & 7, cq = threadIdx.x >> 6;
    int v = ((n * 8 + z) * 8 + y) * 8 + x;
    double acc0 = 0.0, asum = 0.0;
    float acc[4] = {0.f, 0.f, 0.f, 0.f};
    for (int kd = 0; kd < 3; kd++) {
        for (int kh = 0; kh < 3; kh++) {
            int rbase = (kd * 10 + y + kh) * 11 + x;
            const float* wrow = wl + ((kd * 3 + kh) * 3) * 256;
#pragma unroll
            for (int kw = 0; kw < 3; kw++) {
                int s = rbase + kw;
                float4 q0 = til[0][s], q1 = til[1][s], q2 = til[2][s], q3 = til[3][s];
                float xs[16] = {q0.x, q0.y, q0.z, q0.w, q1.x, q1.y, q1.z, q1.w,
                                q2.x, q2.y, q2.z, q2.w, q3.x, q3.y, q3.z, q3.w};
                const float* wt0 = wrow + kw * 256;
                if (cq == 0) {   // wave-uniform branch: wave 0 carries the fp64 gate
#pragma unroll
                    for (int ci = 0; ci < 16; ci++) {
                        float xv = xs[ci];
                        double term = (double)xv * (double)wt0[ci * 16];
                        acc0 += term;
                        asum += fabs(term);
#pragma unroll
                        for (int j = 1; j < 4; j++) acc[j] += xv * wt0[ci * 16 + j];
                    }
                } else {
                    const float* wt = wt0 + cq * 4;
#pragma unroll
                    for (int ci = 0; ci < 16; ci++) {
                        float xv = xs[ci];
                        float4 w4 = *(const float4*)(wt + ci * 16);
                        acc[0] += xv * w4.x; acc[1] += xv * w4.y;
                        acc[2] += xv * w4.z; acc[3] += xv * w4.w;
                    }
                }
            }
        }
    }
    if (cq == 0) {
        u8 pm = pmask[((n * 4 + (z >> 1)) * 4 + (y >> 1)) * 4 + (x >> 1)];
        u8 nm = (pm && (acc0 > -delta * asum)) ? 1 : 0;
        nmsh[y * 8 + x] = nm;
        nmask[v] = nm;
    }
    __syncthreads();
    u8 nm = nmsh[y * 8 + x];
    float4 o;
    if (cq == 0) {
        o = make_float4(nm ? (float)acc0 : 0.f, nm ? acc[1] : 0.f,
                        nm ? acc[2] : 0.f, nm ? acc[3] : 0.f);
    } else {
        o = make_float4(nm ? acc[0] : 0.f, nm ? acc[1] : 0.f,
                        nm ? acc[2] : 0.f, nm ? acc[3] : 0.f);
    }
    *(float4*)(out + (size_t)v * 16 + cq * 4) = o;
}

// ---------------- plain conv k=4 pad(1,2), 16->16; weights staged per-kd slab ----------------
__global__ void conv48_k(const float* __restrict__ in, const float* __restrict__ w,
                         const u8* __restrict__ outmask, float* __restrict__ out) {
    __shared__ float4 til[4][572];   // 36.6 KB
    __shared__ float wl[16 * 256];   // 16 KB
    int z = blockIdx.x & 7, n = blockIdx.x >> 3;
    for (int t = threadIdx.x; t < 484; t += 256) {
        int xx = t % 11;
        int rr = t / 11;
        int yy = rr % 11, zz = rr / 11;
        int gx = xx - 1, gy = yy - 1, gz = z + zz - 1;
        float4 v0 = make_float4(0.f, 0.f, 0.f, 0.f), v1 = v0, v2 = v0, v3 = v0;
        if ((unsigned)gx < 8u && (unsigned)gy < 8u && (unsigned)gz < 8u) {
            const float4* ip = (const float4*)(in + (size_t)(((n * 8 + gz) * 8 + gy) * 8 + gx) * 16);
            v0 = ip[0]; v1 = ip[1]; v2 = ip[2]; v3 = ip[3];
        }
        int s = (zz * 11 + yy) * 13 + xx;
        til[0][s] = v0; til[1][s] = v1; til[2][s] = v2; til[3][s] = v3;
    }
    int x = threadIdx.x & 7, y = (threadIdx.x >> 3) & 7, cq = threadIdx.x >> 6;
    int v = ((n * 8 + z) * 8 + y) * 8 + x;
    u8 om = outmask[v];
    float acc[4] = {0.f, 0.f, 0.f, 0.f};
    for (int kd = 0; kd < 4; kd++) {
        __syncthreads();
        for (int t = threadIdx.x; t < 16 * 256; t += 256) wl[t] = w[kd * 16 * 256 + t];
        __syncthreads();
        for (int kh = 0; kh < 4; kh++) {
            int rbase = (kd * 11 + y + kh) * 13 + x;
            const float* wrow = wl + (kh * 4) * 256;
#pragma unroll
            for (int kw = 0; kw < 4; kw++) {
                int s = rbase + kw;
                float4 q0 = til[0][s], q1 = til[1][s], q2 = til[2][s], q3 = til[3][s];
                float xs[16] = {q0.x, q0.y, q0.z, q0.w, q1.x, q1.y, q1.z, q1.w,
                                q2.x, q2.y, q2.z, q2.w, q3.x, q3.y, q3.z, q3.w};
                const float* wt = wrow + kw * 256 + cq * 4;
#pragma unroll
                for (int ci = 0; ci < 16; ci++) {
                    float xv = xs[ci];
                    float4 w4 = *(const float4*)(wt + ci * 16);
                    acc[0] += xv * w4.x; acc[1] += xv * w4.y;
                    acc[2] += xv * w4.z; acc[3] += xv * w4.w;
                }
            }
        }
    }
    float4 o = make_float4(om ? acc[0] : 0.f, om ? acc[1] : 0.f,
                           om ? acc[2] : 0.f, om ? acc[3] : 0.f);
    *(float4*)(out + (size_t)v * 16 + cq * 4) = o;
}

// ================= remaining generic kernels =================

template <int CIN, int COUT, int SO>
__global__ void down_k(const float* __restrict__ in, const float* __restrict__ w,
                       const u8* __restrict__ outmask, float* __restrict__ out) {
    const int N = 128 * SO * SO * SO;
    constexpr int SI = 2 * SO;
    int v = blockIdx.x * blockDim.x + threadIdx.x;
    if (v >= N) return;
    if (!outmask[v]) {
#pragma unroll
        for (int co = 0; co < COUT; co++) out[(size_t)v * COUT + co] = 0.f;
        return;
    }
    int t = v;
    int x = t % SO; t /= SO;
    int y = t % SO; t /= SO;
    int z = t % SO;
    int n = t / SO;
    float acc[COUT];
#pragma unroll
    for (int co = 0; co < COUT; co++) acc[co] = 0.f;
    for (int kd = 0; kd < 2; kd++)
        for (int kh = 0; kh < 2; kh++)
            for (int kw = 0; kw < 2; kw++) {
                int sv = ((n * SI + 2 * z + kd) * SI + 2 * y + kh) * SI + 2 * x + kw;
                const float* ip = in + (size_t)sv * CIN;
                const float* wpk = w + ((kd * 2 + kh) * 2 + kw) * CIN * COUT;
#pragma unroll
                for (int ci = 0; ci < CIN; ci++) {
                    float xv = ip[ci];
#pragma unroll
                    for (int co = 0; co < COUT; co++) acc[co] += xv * wpk[ci * COUT + co];
                }
            }
#pragma unroll
    for (int co = 0; co < COUT; co++) out[(size_t)v * COUT + co] = acc[co];
}

// ---------------- BN masked reduce, DETERMINISTIC two-pass: per-block partials ----------------
template <int C>
__global__ void bn_reduce_k(const float* __restrict__ x, const u8* __restrict__ m, int N,
                            double* __restrict__ partial) {
    double cnt = 0.0, sx[C], s2[C];
#pragma unroll
    for (int c = 0; c < C; c++) { sx[c] = 0.0; s2[c] = 0.0; }
    int stride = gridDim.x * blockDim.x;
    for (int v = blockIdx.x * blockDim.x + threadIdx.x; v < N; v += stride) {
        float mk = (float)m[v];
        cnt += (double)mk;
        const float4* xp = (const float4*)(x + (size_t)v * C);
#pragma unroll
        for (int q = 0; q < C / 4; q++) {
            float4 r = xp[q];
            float f0 = r.x * mk, f1 = r.y * mk, f2 = r.z * mk, f3 = r.w * mk;
            double x0 = (double)f0, x1 = (double)f1, x2 = (double)f2, x3 = (double)f3;
            sx[4 * q + 0] += x0; s2[4 * q + 0] += x0 * x0;
            sx[4 * q + 1] += x1; s2[4 * q + 1] += x1 * x1;
            sx[4 * q + 2] += x2; s2[4 * q + 2] += x2 * x2;
            sx[4 * q + 3] += x3; s2[4 * q + 3] += x3 * x3;
        }
    }
#pragma unroll
    for (int off = 32; off > 0; off >>= 1) {
        cnt += __shfl_down(cnt, off, 64);
#pragma unroll
        for (int c = 0; c < C; c++) {
            sx[c] += __shfl_down(sx[c], off, 64);
            s2[c] += __shfl_down(s2[c], off, 64);
        }
    }
    __shared__ double sbuf[4][2 * C + 1];
    int wave = threadIdx.x >> 6;
    if ((threadIdx.x & 63) == 0) {
        sbuf[wave][0] = cnt;
#pragma unroll
        for (int c = 0; c < C; c++) {
            sbuf[wave][1 + c] = sx[c];
            sbuf[wave][1 + C + c] = s2[c];
        }
    }
    __syncthreads();
    if (threadIdx.x == 0) {
        double* p = partial + (size_t)blockIdx.x * (2 * C + 1);
        double tcnt = 0.0;
        for (int wv = 0; wv < 4; wv++) tcnt += sbuf[wv][0];
        p[0] = tcnt;
#pragma unroll
        for (int c = 0; c < C; c++) {
            double a = 0.0, b = 0.0;
            for (int wv = 0; wv < 4; wv++) { a += sbuf[wv][1 + c]; b += sbuf[wv][1 + C + c]; }
            p[1 + c] = a;
            p[1 + C + c] = b;
        }
    }
}

// ---------------- BN finalize: fixed-order sum of block partials ----------------
template <int C>
__global__ void bn_final_k(const double* __restrict__ partial, int nblocks,
                           const float* __restrict__ g, const float* __restrict__ b,
                           double* __restrict__ params) {
    int c = threadIdx.x;
    if (c >= C) return;
    double cnt = 0.0, sx = 0.0, s2 = 0.0;
    for (int bk = 0; bk < nblocks; bk++) {
        const double* p = partial + (size_t)bk * (2 * C + 1);
        cnt += p[0];
        sx += p[1 + c];
        s2 += p[1 + C + c];
    }
    if (cnt < 1.0) cnt = 1.0;
    double mean = sx / cnt;
    double var = s2 / cnt - mean * mean;
    double sc = (double)g[c] / sqrt(var + 1e-4);
    params[c] = sc;
    params[C + c] = (double)b[c] - mean * sc;
}

// ---------------- hidden: NDHWC (4^3, 32ch) -> NCDHW flat ----------------
__global__ void hidden_k(const float* __restrict__ x, float* __restrict__ out) {
    int i = blockIdx.x * blockDim.x + threadIdx.x;
    if (i >= 128 * 2048) return;
    int b = i >> 11;
    int r = i & 2047;
    int c = r >> 6;
    int s = r & 63;
    int d = s >> 4;
    int h = (s >> 2) & 3;
    int w = s & 3;
    out[i] = x[((((b * 4 + d) * 4 + h) * 4 + w) << 5) + c];
}

extern "C" void kernel_launch(void* const* d_in, const int* in_sizes, int n_in,
                              void* d_out, int out_size, void* d_ws, size_t ws_size,
                              hipStream_t stream) {
    const float* vox = (const float*)d_in[0];
    const int* mraw = (const int*)d_in[1];
    const float* wp = (const float*)d_in[2];
    const float* g_e0 = (const float*)d_in[3];
    const float* b_e0 = (const float*)d_in[4];
    const float* ws_e0 = (const float*)d_in[5];
    const float* wd_e0 = (const float*)d_in[6];
    const float* g_e1 = (const float*)d_in[7];
    const float* b_e1 = (const float*)d_in[8];
    const float* ws_e1 = (const float*)d_in[9];
    const float* wd_e1 = (const float*)d_in[10];
    const float* g_e2 = (const float*)d_in[11];
    const float* b_e2 = (const float*)d_in[12];
    const float* ws_e2 = (const float*)d_in[13];
    const float* wd_e2 = (const float*)d_in[14];
    const float* g_d0 = (const float*)d_in[15];
    const float* b_d0 = (const float*)d_in[16];
    const float* wu_d0 = (const float*)d_in[17];
    const float* ws3_d0 = (const float*)d_in[18];
    const float* ws4_d0 = (const float*)d_in[19];
    const float* g_d1 = (const float*)d_in[20];
    const float* b_d1 = (const float*)d_in[21];
    const float* wu_d1 = (const float*)d_in[22];
    const float* ws3_d1 = (const float*)d_in[23];
    const float* ws4_d1 = (const float*)d_in[24];
    const float* g_d2 = (const float*)d_in[25];
    const float* b_d2 = (const float*)d_in[26];
    const float* wu_d2 = (const float*)d_in[27];
    const float* ws3_d2 = (const float*)d_in[28];
    const float* ws4_d2 = (const float*)d_in[29];
    const float* wo = (const float*)d_in[30];
    float* out = (float*)d_out;

    // ---- workspace: fp32 tensors + fp64 partials/params + u8 masks (~153 MB) ----
    float* wsf = (float*)d_ws;
    size_t offf = 0;
    auto allocf = [&](size_t n) { float* p = wsf + offf; offf += n; return p; };
    float* R1 = allocf(16777216);
    float* R2 = allocf(16777216);
    float* S1 = allocf(1048576);
    float* S2 = allocf(1048576);
    float* T = allocf(262144);
    double* wsd = (double*)(wsf + offf);
    double* partial = wsd;          // up to 256 blocks x (2*32+1) doubles
    double* params = wsd + 16640;
    u8* wsm = (u8*)(wsd + 16640 + 128);
    size_t offm = 0;
    auto allocm = [&](size_t n) { u8* p = wsm + offm; offm += n; return p; };
    u8* m32 = allocm(4194304);
    u8* m16 = allocm(524288);
    u8* m8 = allocm(65536);
    u8* m4 = allocm(8192);
    u8* mD8 = allocm(65536);
    u8* mD16 = allocm(524288);
    u8* mD32 = allocm(4194304);

    const int N32 = 128 * 32768;
    const int N16 = 128 * 4096;
    const int N8 = 128 * 512;
    const int N4 = 128 * 64;
    auto gs = [](int n) { return dim3((n + 255) / 256); };
    auto rbn = [](int n) { int bl = (n + 255) / 256; return bl > 256 ? 256 : bl; };
    dim3 blk(256);
    dim3 tgrid(4096);               // 32^3: 128 images x 4 y-tiles x 8 z-tiles
    dim3 grid16(1024);              // 16^3: 128 images x 2 y-tiles x 4 z-tiles
    dim3 grid8(1024);               // 8^3: 128 images x 8 z-planes

    // masks
    mask_init_k<<<gs(N32), blk, 0, stream>>>(mraw, m32, N32);
    pool_k<16><<<gs(N16), blk, 0, stream>>>(m32, m16);
    pool_k<8><<<gs(N8), blk, 0, stream>>>(m16, m8);
    pool_k<4><<<gs(N4), blk, 0, stream>>>(m8, m4);

    // ---- encoder stage 0 @32^3: prep -> BN stats -> fused convbn+down -> R2 (16^3 8ch) ----
    prep4t_k<<<tgrid, blk, 0, stream>>>(vox, m32, wp, R1);
    int nb0 = rbn(N32);
    bn_reduce_k<4><<<dim3(nb0), blk, 0, stream>>>(R1, m32, N32, partial);
    bn_final_k<4><<<1, 64, 0, stream>>>(partial, nb0, g_e0, b_e0, params);
    convbndown4t_k<<<tgrid, blk, 0, stream>>>(R1, ws_e0, m32, params, wd_e0, m16, R2);

    // ---- encoder stage 1 @16^3: fused convbn+down -> S1 (8^3 16ch) ----
    int nb1 = rbn(N16);
    bn_reduce_k<8><<<dim3(nb1), blk, 0, stream>>>(R2, m16, N16, partial);
    bn_final_k<8><<<1, 64, 0, stream>>>(partial, nb1, g_e1, b_e1, params);
    convbndown16t_k<<<grid16, blk, 0, stream>>>(R2, ws_e1, m16, params, wd_e1, m8, S1);

    // ---- encoder stage 2 @8^3: convbn -> S2; down -> T (4^3 32ch) ----
    int nb2 = rbn(N8);
    bn_reduce_k<16><<<dim3(nb2), blk, 0, stream>>>(S1, m8, N8, partial);
    bn_final_k<16><<<1, 64, 0, stream>>>(partial, nb2, g_e2, b_e2, params);
    convbn8_k<<<grid8, blk, 0, stream>>>(S1, ws_e2, m8, params, S2);
    down_k<16, 32, 4><<<gs(N4), blk, 0, stream>>>(S2, wd_e2, m4, T);

    // ---- hidden ----
    hidden_k<<<gs(128 * 2048), blk, 0, stream>>>(T, out);

    // ---- decoder stage 0 (4^3 -> 8^3), fused upbn at stage-in, band gate delta=4e-7 ----
    int nb3 = rbn(N4);
    bn_reduce_k<32><<<dim3(nb3), blk, 0, stream>>>(T, m4, N4, partial);
    bn_final_k<32><<<1, 64, 0, stream>>>(partial, nb3, g_d0, b_d0, params);
    conv3s8f_k<<<grid8, blk, 0, stream>>>(T, wu_d0, ws3_d0, m4, mD8, S2, params, 4e-7);
    conv48_k<<<grid8, blk, 0, stream>>>(S2, ws4_d0, mD8, S1);

    // ---- decoder stage 1 (8^3 -> 16^3), fused upbn at stage-in, band gate delta=4e-7 ----
    int nb4 = rbn(N8);
    bn_reduce_k<16><<<dim3(nb4), blk, 0, stream>>>(S1, mD8, N8, partial);
    bn_final_k<16><<<1, 64, 0, stream>>>(partial, nb4, g_d1, b_d1, params);
    conv3s16tf_k<<<grid16, blk, 0, stream>>>(S1, wu_d1, ws3_d1, mD8, mD16, R2, params, 4e-7);
    conv416t_k<<<grid16, blk, 0, stream>>>(R2, ws4_d1, mD16, R1);

    // ---- decoder stage 2 (16^3 -> 32^3), fused upbn at stage-in, exact gate ----
    int nb5 = rbn(N16);
    bn_reduce_k<8><<<dim3(nb5), blk, 0, stream>>>(R1, mD16, N16, partial);
    bn_final_k<8><<<1, 64, 0, stream>>>(partial, nb5, g_d2, b_d2, params);
    conv3s4tf_k<<<tgrid, blk, 0, stream>>>(R1, wu_d2, ws3_d2, mD16, mD32, R2, params);
    conv4x4t_k<<<tgrid, blk, 0, stream>>>(R2, ws4_d2, mD32, R1);
    outconv4t_k<<<tgrid, blk, 0, stream>>>(R1, wo, mD32, out + 262144);
}

// Round 10
// 1274.376 us; speedup vs baseline: 1.0899x; 1.0899x over previous
//
#include <hip/hip_runtime.h>

using u8 = unsigned char;

// ---------------- mask init: m = (maskraw == 0) ----------------
__global__ void mask_init_k(const int* __restrict__ mr, u8* __restrict__ m, int N) {
    int i = blockIdx.x * blockDim.x + threadIdx.x;
    if (i < N) m[i] = (mr[i] == 0) ? 1 : 0;
}

// ---------------- mask pool 2x2x2 (logical OR), full batch ----------------
template <int SO>
__global__ void pool_k(const u8* __restrict__ mi, u8* __restrict__ mo) {
    const int N = 128 * SO * SO * SO;
    constexpr int SI = 2 * SO;
    int v = blockIdx.x * blockDim.x + threadIdx.x;
    if (v >= N) return;
    int t = v;
    int x = t % SO; t /= SO;
    int y = t % SO; t /= SO;
    int z = t % SO;
    int n = t / SO;
    u8 m = 0;
    for (int kd = 0; kd < 2; kd++)
        for (int kh = 0; kh < 2; kh++)
            for (int kw = 0; kw < 2; kw++)
                m |= mi[((n * SI + 2 * z + kd) * SI + 2 * y + kh) * SI + 2 * x + kw];
    mo[v] = m;
}

// ================= 32^3 LDS-tiled kernels =================

// ---------------- prepare conv 1->4, k=3 (input masked at stage-in) ----------------
__global__ void prep4t_k(const float* __restrict__ vox, const u8* __restrict__ m,
                         const float* __restrict__ wp, float* __restrict__ out) {
    __shared__ float til[6 * 10 * 35];   // 8.4 KB
    int bid = blockIdx.x;
    int y0 = (bid & 3) << 3, z0 = ((bid >> 2) & 7) << 2, n = bid >> 5;
    for (int t = threadIdx.x; t < 6 * 10 * 35; t += 256) {
        int x_ = t % 35;
        int rr = t / 35;
        int yy = rr % 10, zz = rr / 10;
        int gx = x_ - 1, gy = y0 + yy - 1, gz = z0 + zz - 1;
        float v = 0.f;
        if ((unsigned)gx < 32u && (unsigned)gy < 32u && (unsigned)gz < 32u) {
            int gi = ((n * 32 + gz) * 32 + gy) * 32 + gx;
            if (m[gi]) v = vox[gi];
        }
        til[t] = v;
    }
    __syncthreads();
    int tx = threadIdx.x;
    int xg = tx & 7, ly = (tx >> 3) & 7, lz = tx >> 6;
    int xb = xg << 2;
    int vbase = ((n * 32 + z0 + lz) * 32 + y0 + ly) * 32 + xb;
    u8 om[4];
#pragma unroll
    for (int j = 0; j < 4; j++) om[j] = m[vbase + j];
    float acc[4][4];
#pragma unroll
    for (int j = 0; j < 4; j++)
#pragma unroll
        for (int co = 0; co < 4; co++) acc[j][co] = 0.f;
    for (int kd = 0; kd < 3; kd++) {
        for (int kh = 0; kh < 3; kh++) {
            const float* rowp = &til[((lz + kd) * 10 + ly + kh) * 35 + xb];
            float col[6];
#pragma unroll
            for (int c = 0; c < 6; c++) col[c] = rowp[c];
            const float* wrow = wp + ((kd * 3 + kh) * 3) * 4;
#pragma unroll
            for (int kw = 0; kw < 3; kw++) {
                const float* wt = wrow + kw * 4;
#pragma unroll
                for (int j = 0; j < 4; j++) {
                    float xv = col[j + kw];
#pragma unroll
                    for (int co = 0; co < 4; co++) acc[j][co] += xv * wt[co];
                }
            }
        }
    }
#pragma unroll
    for (int j = 0; j < 4; j++) {
        float4 o = make_float4(om[j] ? acc[j][0] : 0.f, om[j] ? acc[j][1] : 0.f,
                               om[j] ? acc[j][2] : 0.f, om[j] ? acc[j][3] : 0.f);
        *(float4*)(out + (size_t)(vbase + j) * 4) = o;
    }
}

// ---------------- conv k=3, 4->4, BN(affine+ReLU+mask) applied at stage-in ----------------
__global__ void convbn4t_k(const float* __restrict__ in, const float* __restrict__ w,
                           const u8* __restrict__ mask, const double* __restrict__ params,
                           float* __restrict__ out) {
    __shared__ float4 til[6 * 10 * 35];  // 33.6 KB
    float sc[4], sh[4];
#pragma unroll
    for (int c = 0; c < 4; c++) { sc[c] = (float)params[c]; sh[c] = (float)params[4 + c]; }
    int bid = blockIdx.x;
    int y0 = (bid & 3) << 3, z0 = ((bid >> 2) & 7) << 2, n = bid >> 5;
    for (int t = threadIdx.x; t < 6 * 10 * 35; t += 256) {
        int x_ = t % 35;
        int rr = t / 35;
        int yy = rr % 10, zz = rr / 10;
        int gx = x_ - 1, gy = y0 + yy - 1, gz = z0 + zz - 1;
        float4 v = make_float4(0.f, 0.f, 0.f, 0.f);
        if ((unsigned)gx < 32u && (unsigned)gy < 32u && (unsigned)gz < 32u) {
            int gi = ((n * 32 + gz) * 32 + gy) * 32 + gx;
            if (mask[gi]) {
                float4 r = *(const float4*)(in + (size_t)gi * 4);
                v.x = fmaxf(r.x * sc[0] + sh[0], 0.f);
                v.y = fmaxf(r.y * sc[1] + sh[1], 0.f);
                v.z = fmaxf(r.z * sc[2] + sh[2], 0.f);
                v.w = fmaxf(r.w * sc[3] + sh[3], 0.f);
            }
        }
        til[t] = v;
    }
    __syncthreads();
    int tx = threadIdx.x;
    int xg = tx & 7, ly = (tx >> 3) & 7, lz = tx >> 6;
    int xb = xg << 2;
    int vbase = ((n * 32 + z0 + lz) * 32 + y0 + ly) * 32 + xb;
    u8 om[4];
#pragma unroll
    for (int j = 0; j < 4; j++) om[j] = mask[vbase + j];
    float acc[4][4];
#pragma unroll
    for (int j = 0; j < 4; j++)
#pragma unroll
        for (int co = 0; co < 4; co++) acc[j][co] = 0.f;
    for (int kd = 0; kd < 3; kd++) {
        for (int kh = 0; kh < 3; kh++) {
            const float4* rowp = &til[((lz + kd) * 10 + ly + kh) * 35 + xb];
            float col[6][4];
#pragma unroll
            for (int c = 0; c < 6; c++) {
                float4 t4 = rowp[c];
                col[c][0] = t4.x; col[c][1] = t4.y; col[c][2] = t4.z; col[c][3] = t4.w;
            }
            const float* wrow = w + ((kd * 3 + kh) * 3) * 16;
#pragma unroll
            for (int kw = 0; kw < 3; kw++) {
                const float* wt = wrow + kw * 16;
#pragma unroll
                for (int j = 0; j < 4; j++) {
#pragma unroll
                    for (int ci = 0; ci < 4; ci++) {
                        float xv = col[j + kw][ci];
#pragma unroll
                        for (int co = 0; co < 4; co++) acc[j][co] += xv * wt[ci * 4 + co];
                    }
                }
            }
        }
    }
#pragma unroll
    for (int j = 0; j < 4; j++) {
        float4 o = make_float4(om[j] ? acc[j][0] : 0.f, om[j] ? acc[j][1] : 0.f,
                               om[j] ? acc[j][2] : 0.f, om[j] ? acc[j][3] : 0.f);
        *(float4*)(out + (size_t)(vbase + j) * 4) = o;
    }
}

// ---------------- conv k=3 4->4 + fused sparsify (fp64 sum, EXACT gate) ----------------
// SoA channel-plane LDS: fp64 register pressure makes the compiler lower float4 LDS
// reads as scalar b32, and a float4 array's dword lanes land on only 8 banks (8-way
// conflict, 17.7M cycles measured). Scalar planes with odd row stride (35 % 32 = 3)
// spread lanes 2-way (free). FMA order unchanged -> bit-identical.
__global__ void conv3s4t_k(const float* __restrict__ in, const float* __restrict__ w,
                           const u8* __restrict__ pmask, u8* __restrict__ nmask,
                           float* __restrict__ out) {
    __shared__ float til[4][2100];   // 4 planes x 6*10*35, 33.6 KB
    int bid = blockIdx.x;
    int y0 = (bid & 3) << 3, z0 = ((bid >> 2) & 7) << 2, n = bid >> 5;
    for (int t = threadIdx.x; t < 2100; t += 256) {
        int x_ = t % 35;
        int rr = t / 35;
        int yy = rr % 10, zz = rr / 10;
        int gx = x_ - 1, gy = y0 + yy - 1, gz = z0 + zz - 1;
        float4 v = make_float4(0.f, 0.f, 0.f, 0.f);
        if ((unsigned)gx < 32u && (unsigned)gy < 32u && (unsigned)gz < 32u)
            v = *(const float4*)(in + (size_t)(((n * 32 + gz) * 32 + gy) * 32 + gx) * 4);
        til[0][t] = v.x; til[1][t] = v.y; til[2][t] = v.z; til[3][t] = v.w;
    }
    __syncthreads();
    int tx = threadIdx.x;
    int xg = tx & 7, ly = (tx >> 3) & 7, lz = tx >> 6;
    int xb = xg << 2;
    int gy = y0 + ly, gz = z0 + lz;
    int vbase = ((n * 32 + gz) * 32 + gy) * 32 + xb;
    int pbase = ((n * 16 + (gz >> 1)) * 16 + (gy >> 1)) * 16 + (xb >> 1);
    u8 pm[4];
    pm[0] = pm[1] = pmask[pbase];
    pm[2] = pm[3] = pmask[pbase + 1];
    double acc0[4];
    float accf[4][4];
#pragma unroll
    for (int j = 0; j < 4; j++) {
        acc0[j] = 0.0;
#pragma unroll
        for (int co = 0; co < 4; co++) accf[j][co] = 0.f;
    }
    for (int kd = 0; kd < 3; kd++) {
        for (int kh = 0; kh < 3; kh++) {
            int rbase = ((lz + kd) * 10 + ly + kh) * 35 + xb;
            float col[6][4];
#pragma unroll
            for (int c = 0; c < 6; c++) {
#pragma unroll
                for (int ci = 0; ci < 4; ci++) col[c][ci] = til[ci][rbase + c];
            }
            const float* wrow = w + ((kd * 3 + kh) * 3) * 16;
#pragma unroll
            for (int kw = 0; kw < 3; kw++) {
                const float* wt = wrow + kw * 16;
#pragma unroll
                for (int j = 0; j < 4; j++) {
#pragma unroll
                    for (int ci = 0; ci < 4; ci++) {
                        float xv = col[j + kw][ci];
                        acc0[j] += (double)xv * (double)wt[ci * 4 + 0];
#pragma unroll
                        for (int co = 1; co < 4; co++) accf[j][co] += xv * wt[ci * 4 + co];
                    }
                }
            }
        }
    }
    unsigned nm4 = 0;
#pragma unroll
    for (int j = 0; j < 4; j++) {
        u8 nm = (pm[j] && (acc0[j] > 0.0)) ? 1 : 0;
        nm4 |= ((unsigned)nm) << (8 * j);
        float4 o = make_float4(nm ? (float)acc0[j] : 0.f, nm ? accf[j][1] : 0.f,
                               nm ? accf[j][2] : 0.f, nm ? accf[j][3] : 0.f);
        *(float4*)(out + (size_t)(vbase + j) * 4) = o;
    }
    *(unsigned*)(nmask + vbase) = nm4;   // vbase % 4 == 0, nmask 4B-aligned
}

// ---------------- plain conv 4->4, k=4 pad(1,2) ----------------
__global__ void conv4x4t_k(const float* __restrict__ in, const float* __restrict__ w,
                           const u8* __restrict__ outmask, float* __restrict__ out) {
    __shared__ float4 til[7 * 11 * 35];  // 43.1 KB
    int bid = blockIdx.x;
    int y0 = (bid & 3) << 3, z0 = ((bid >> 2) & 7) << 2, n = bid >> 5;
    for (int t = threadIdx.x; t < 7 * 11 * 35; t += 256) {
        int x_ = t % 35;
        int rr = t / 35;
        int yy = rr % 11, zz = rr / 11;
        int gx = x_ - 1, gy = y0 + yy - 1, gz = z0 + zz - 1;
        float4 v = make_float4(0.f, 0.f, 0.f, 0.f);
        if ((unsigned)gx < 32u && (unsigned)gy < 32u && (unsigned)gz < 32u)
            v = *(const float4*)(in + (size_t)(((n * 32 + gz) * 32 + gy) * 32 + gx) * 4);
        til[t] = v;
    }
    __syncthreads();
    int tx = threadIdx.x;
    int xg = tx & 7, ly = (tx >> 3) & 7, lz = tx >> 6;
    int xb = xg << 2;
    int vbase = ((n * 32 + z0 + lz) * 32 + y0 + ly) * 32 + xb;
    u8 om[4];
#pragma unroll
    for (int j = 0; j < 4; j++) om[j] = outmask[vbase + j];
    float acc[4][4];
#pragma unroll
    for (int j = 0; j < 4; j++)
#pragma unroll
        for (int co = 0; co < 4; co++) acc[j][co] = 0.f;
    for (int kd = 0; kd < 4; kd++) {
        for (int kh = 0; kh < 4; kh++) {
            const float4* rowp = &til[((lz + kd) * 11 + ly + kh) * 35 + xb];
            float col[7][4];
#pragma unroll
            for (int c = 0; c < 7; c++) {
                float4 t4 = rowp[c];
                col[c][0] = t4.x; col[c][1] = t4.y; col[c][2] = t4.z; col[c][3] = t4.w;
            }
            const float* wrow = w + ((kd * 4 + kh) * 4) * 16;
#pragma unroll
            for (int kw = 0; kw < 4; kw++) {
                const float* wt = wrow + kw * 16;
#pragma unroll
                for (int j = 0; j < 4; j++) {
#pragma unroll
                    for (int ci = 0; ci < 4; ci++) {
                        float xv = col[j + kw][ci];
#pragma unroll
                        for (int co = 0; co < 4; co++) acc[j][co] += xv * wt[ci * 4 + co];
                    }
                }
            }
        }
    }
#pragma unroll
    for (int j = 0; j < 4; j++) {
        float4 o = make_float4(om[j] ? acc[j][0] : 0.f, om[j] ? acc[j][1] : 0.f,
                               om[j] ? acc[j][2] : 0.f, om[j] ? acc[j][3] : 0.f);
        *(float4*)(out + (size_t)(vbase + j) * 4) = o;
    }
}

// ---------------- final output conv k=3, 4->1 ----------------
__global__ void outconv4t_k(const float* __restrict__ in, const float* __restrict__ w,
                            const u8* __restrict__ mask, float* __restrict__ out) {
    __shared__ float4 til[6 * 10 * 35];  // 33.6 KB
    int bid = blockIdx.x;
    int y0 = (bid & 3) << 3, z0 = ((bid >> 2) & 7) << 2, n = bid >> 5;
    for (int t = threadIdx.x; t < 6 * 10 * 35; t += 256) {
        int x_ = t % 35;
        int rr = t / 35;
        int yy = rr % 10, zz = rr / 10;
        int gx = x_ - 1, gy = y0 + yy - 1, gz = z0 + zz - 1;
        float4 v = make_float4(0.f, 0.f, 0.f, 0.f);
        if ((unsigned)gx < 32u && (unsigned)gy < 32u && (unsigned)gz < 32u)
            v = *(const float4*)(in + (size_t)(((n * 32 + gz) * 32 + gy) * 32 + gx) * 4);
        til[t] = v;
    }
    __syncthreads();
    int tx = threadIdx.x;
    int xg = tx & 7, ly = (tx >> 3) & 7, lz = tx >> 6;
    int xb = xg << 2;
    int vbase = ((n * 32 + z0 + lz) * 32 + y0 + ly) * 32 + xb;
    u8 om[4];
#pragma unroll
    for (int j = 0; j < 4; j++) om[j] = mask[vbase + j];
    float acc[4] = {0.f, 0.f, 0.f, 0.f};
    for (int kd = 0; kd < 3; kd++) {
        for (int kh = 0; kh < 3; kh++) {
            const float4* rowp = &til[((lz + kd) * 10 + ly + kh) * 35 + xb];
            float col[6][4];
#pragma unroll
            for (int c = 0; c < 6; c++) {
                float4 t4 = rowp[c];
                col[c][0] = t4.x; col[c][1] = t4.y; col[c][2] = t4.z; col[c][3] = t4.w;
            }
            const float* wrow = w + ((kd * 3 + kh) * 3) * 4;
#pragma unroll
            for (int kw = 0; kw < 3; kw++) {
                const float* wt = wrow + kw * 4;
#pragma unroll
                for (int j = 0; j < 4; j++) {
#pragma unroll
                    for (int ci = 0; ci < 4; ci++) acc[j] += col[j + kw][ci] * wt[ci];
                }
            }
        }
    }
    float4 o = make_float4(om[0] ? acc[0] : 0.f, om[1] ? acc[1] : 0.f,
                           om[2] ? acc[2] : 0.f, om[3] ? acc[3] : 0.f);
    *(float4*)(out + vbase) = o;   // vbase % 4 == 0
}

// ================= 16^3 LDS-tiled kernels (8ch), XPT=2 =================

// ---------------- conv k=3, 8->8, BN(affine+ReLU+mask) at stage-in ----------------
__global__ void convbn16t_k(const float* __restrict__ in, const float* __restrict__ w,
                            const u8* __restrict__ mask, const double* __restrict__ params,
                            float* __restrict__ out) {
    __shared__ float4 til[2][1140];   // 36.5 KB
    __shared__ float wl[1728];        // 6.9 KB
    float sc[8], sh[8];
#pragma unroll
    for (int c = 0; c < 8; c++) { sc[c] = (float)params[c]; sh[c] = (float)params[8 + c]; }
    int bid = blockIdx.x;
    int y0 = (bid & 1) << 3, z0 = ((bid >> 1) & 3) << 2, n = bid >> 3;
    for (int t = threadIdx.x; t < 1728; t += 256) wl[t] = w[t];
    for (int t = threadIdx.x; t < 1140; t += 256) {
        int x_ = t % 19;
        int rr = t / 19;
        int yy = rr % 10, zz = rr / 10;
        int gx = x_ - 1, gy = y0 + yy - 1, gz = z0 + zz - 1;
        float v[8];
#pragma unroll
        for (int c = 0; c < 8; c++) v[c] = 0.f;
        if ((unsigned)gx < 16u && (unsigned)gy < 16u && (unsigned)gz < 16u) {
            int gi = ((n * 16 + gz) * 16 + gy) * 16 + gx;
            if (mask[gi]) {
                const float* ip = in + (size_t)gi * 8;
#pragma unroll
                for (int c = 0; c < 8; c++) v[c] = fmaxf(ip[c] * sc[c] + sh[c], 0.f);
            }
        }
        til[0][t] = make_float4(v[0], v[1], v[2], v[3]);
        til[1][t] = make_float4(v[4], v[5], v[6], v[7]);
    }
    __syncthreads();
    int xg = threadIdx.x & 7, ly = (threadIdx.x >> 3) & 7, lz = threadIdx.x >> 6;
    int xb = xg << 1;
    int vbase = ((n * 16 + z0 + lz) * 16 + y0 + ly) * 16 + xb;
    u8 om[2] = {mask[vbase], mask[vbase + 1]};
    float acc[2][8];
#pragma unroll
    for (int j = 0; j < 2; j++)
#pragma unroll
        for (int co = 0; co < 8; co++) acc[j][co] = 0.f;
    for (int kd = 0; kd < 3; kd++) {
        for (int kh = 0; kh < 3; kh++) {
            int rbase = ((lz + kd) * 10 + ly + kh) * 19 + xb;
            float col[4][8];
#pragma unroll
            for (int c = 0; c < 4; c++) {
                float4 a = til[0][rbase + c], b = til[1][rbase + c];
                col[c][0] = a.x; col[c][1] = a.y; col[c][2] = a.z; col[c][3] = a.w;
                col[c][4] = b.x; col[c][5] = b.y; col[c][6] = b.z; col[c][7] = b.w;
            }
            const float* wrow = wl + ((kd * 3 + kh) * 3) * 64;
#pragma unroll
            for (int kw = 0; kw < 3; kw++) {
                const float* wt = wrow + kw * 64;
#pragma unroll
                for (int j = 0; j < 2; j++) {
#pragma unroll
                    for (int ci = 0; ci < 8; ci++) {
                        float xv = col[j + kw][ci];
#pragma unroll
                        for (int co = 0; co < 8; co++) acc[j][co] += xv * wt[ci * 8 + co];
                    }
                }
            }
        }
    }
#pragma unroll
    for (int j = 0; j < 2; j++) {
        float* op = out + (size_t)(vbase + j) * 8;
        float4 o0 = make_float4(om[j] ? acc[j][0] : 0.f, om[j] ? acc[j][1] : 0.f,
                                om[j] ? acc[j][2] : 0.f, om[j] ? acc[j][3] : 0.f);
        float4 o1 = make_float4(om[j] ? acc[j][4] : 0.f, om[j] ? acc[j][5] : 0.f,
                                om[j] ? acc[j][6] : 0.f, om[j] ? acc[j][7] : 0.f);
        ((float4*)op)[0] = o0;
        ((float4*)op)[1] = o1;
    }
}

// ---------------- conv k=3, 8->8 + fused sparsify (fp64 band gate, pmask @8^3),
// SoA channel-plane LDS (same conflict fix as conv3s4t) ----------------
__global__ void conv3s16t_k(const float* __restrict__ in, const float* __restrict__ w,
                            const u8* __restrict__ pmask, u8* __restrict__ nmask,
                            float* __restrict__ out, double delta) {
    __shared__ float til[8][1140];    // 8 planes x 6*10*19, 36.5 KB
    __shared__ float wl[1728];        // 6.9 KB
    int bid = blockIdx.x;
    int y0 = (bid & 1) << 3, z0 = ((bid >> 1) & 3) << 2, n = bid >> 3;
    for (int t = threadIdx.x; t < 1728; t += 256) wl[t] = w[t];
    for (int t = threadIdx.x; t < 1140; t += 256) {
        int x_ = t % 19;
        int rr = t / 19;
        int yy = rr % 10, zz = rr / 10;
        int gx = x_ - 1, gy = y0 + yy - 1, gz = z0 + zz - 1;
        float4 a = make_float4(0.f, 0.f, 0.f, 0.f), b = a;
        if ((unsigned)gx < 16u && (unsigned)gy < 16u && (unsigned)gz < 16u) {
            const float4* ip = (const float4*)(in + (size_t)(((n * 16 + gz) * 16 + gy) * 16 + gx) * 8);
            a = ip[0]; b = ip[1];
        }
        til[0][t] = a.x; til[1][t] = a.y; til[2][t] = a.z; til[3][t] = a.w;
        til[4][t] = b.x; til[5][t] = b.y; til[6][t] = b.z; til[7][t] = b.w;
    }
    __syncthreads();
    int xg = threadIdx.x & 7, ly = (threadIdx.x >> 3) & 7, lz = threadIdx.x >> 6;
    int xb = xg << 1;
    int gy = y0 + ly, gz = z0 + lz;
    int vbase = ((n * 16 + gz) * 16 + gy) * 16 + xb;
    u8 pm = pmask[((n * 8 + (gz >> 1)) * 8 + (gy >> 1)) * 8 + (xb >> 1)];
    double acc0[2], asum[2];
    float accf[2][8];
#pragma unroll
    for (int j = 0; j < 2; j++) {
        acc0[j] = 0.0; asum[j] = 0.0;
#pragma unroll
        for (int co = 0; co < 8; co++) accf[j][co] = 0.f;
    }
    for (int kd = 0; kd < 3; kd++) {
        for (int kh = 0; kh < 3; kh++) {
            int rbase = ((lz + kd) * 10 + ly + kh) * 19 + xb;
            float col[4][8];
#pragma unroll
            for (int c = 0; c < 4; c++) {
#pragma unroll
                for (int ci = 0; ci < 8; ci++) col[c][ci] = til[ci][rbase + c];
            }
            const float* wrow = wl + ((kd * 3 + kh) * 3) * 64;
#pragma unroll
            for (int kw = 0; kw < 3; kw++) {
                const float* wt = wrow + kw * 64;
#pragma unroll
                for (int j = 0; j < 2; j++) {
#pragma unroll
                    for (int ci = 0; ci < 8; ci++) {
                        float xv = col[j + kw][ci];
                        double term = (double)xv * (double)wt[ci * 8 + 0];
                        acc0[j] += term;
                        asum[j] += fabs(term);
#pragma unroll
                        for (int co = 1; co < 8; co++) accf[j][co] += xv * wt[ci * 8 + co];
                    }
                }
            }
        }
    }
    unsigned short nm2 = 0;
#pragma unroll
    for (int j = 0; j < 2; j++) {
        u8 nm = (pm && (acc0[j] > -delta * asum[j])) ? 1 : 0;
        nm2 |= ((unsigned short)nm) << (8 * j);
        float* op = out + (size_t)(vbase + j) * 8;
        float4 o0 = make_float4(nm ? (float)acc0[j] : 0.f, nm ? accf[j][1] : 0.f,
                                nm ? accf[j][2] : 0.f, nm ? accf[j][3] : 0.f);
        float4 o1 = make_float4(nm ? accf[j][4] : 0.f, nm ? accf[j][5] : 0.f,
                                nm ? accf[j][6] : 0.f, nm ? accf[j][7] : 0.f);
        ((float4*)op)[0] = o0;
        ((float4*)op)[1] = o1;
    }
    *(unsigned short*)(nmask + vbase) = nm2;   // vbase even
}

// ---------------- plain conv k=4 pad(1,2), 8->8; weights staged per-kd slab ----------------
__global__ void conv416t_k(const float* __restrict__ in, const float* __restrict__ w,
                           const u8* __restrict__ outmask, float* __restrict__ out) {
    __shared__ float4 til[2][1463];   // 46.8 KB
    __shared__ float wl[1024];        // 4 KB
    int bid = blockIdx.x;
    int y0 = (bid & 1) << 3, z0 = ((bid >> 1) & 3) << 2, n = bid >> 3;
    for (int t = threadIdx.x; t < 1463; t += 256) {
        int x_ = t % 19;
        int rr = t / 19;
        int yy = rr % 11, zz = rr / 11;
        int gx = x_ - 1, gy = y0 + yy - 1, gz = z0 + zz - 1;
        float4 a = make_float4(0.f, 0.f, 0.f, 0.f), b = a;
        if ((unsigned)gx < 16u && (unsigned)gy < 16u && (unsigned)gz < 16u) {
            const float4* ip = (const float4*)(in + (size_t)(((n * 16 + gz) * 16 + gy) * 16 + gx) * 8);
            a = ip[0]; b = ip[1];
        }
        til[0][t] = a;
        til[1][t] = b;
    }
    int xg = threadIdx.x & 7, ly = (threadIdx.x >> 3) & 7, lz = threadIdx.x >> 6;
    int xb = xg << 1;
    int vbase = ((n * 16 + z0 + lz) * 16 + y0 + ly) * 16 + xb;
    u8 om[2] = {outmask[vbase], outmask[vbase + 1]};
    float acc[2][8];
#pragma unroll
    for (int j = 0; j < 2; j++)
#pragma unroll
        for (int co = 0; co < 8; co++) acc[j][co] = 0.f;
    for (int kd = 0; kd < 4; kd++) {
        __syncthreads();
        for (int t = threadIdx.x; t < 1024; t += 256) wl[t] = w[kd * 1024 + t];
        __syncthreads();
        for (int kh = 0; kh < 4; kh++) {
            int rbase = ((lz + kd) * 11 + ly + kh) * 19 + xb;
            float col[5][8];
#pragma unroll
            for (int c = 0; c < 5; c++) {
                float4 a = til[0][rbase + c], b = til[1][rbase + c];
                col[c][0] = a.x; col[c][1] = a.y; col[c][2] = a.z; col[c][3] = a.w;
                col[c][4] = b.x; col[c][5] = b.y; col[c][6] = b.z; col[c][7] = b.w;
            }
            const float* wrow = wl + (kh * 4) * 64;
#pragma unroll
            for (int kw = 0; kw < 4; kw++) {
                const float* wt = wrow + kw * 64;
#pragma unroll
                for (int j = 0; j < 2; j++) {
#pragma unroll
                    for (int ci = 0; ci < 8; ci++) {
                        float xv = col[j + kw][ci];
#pragma unroll
                        for (int co = 0; co < 8; co++) acc[j][co] += xv * wt[ci * 8 + co];
                    }
                }
            }
        }
    }
#pragma unroll
    for (int j = 0; j < 2; j++) {
        float* op = out + (size_t)(vbase + j) * 8;
        float4 o0 = make_float4(om[j] ? acc[j][0] : 0.f, om[j] ? acc[j][1] : 0.f,
                                om[j] ? acc[j][2] : 0.f, om[j] ? acc[j][3] : 0.f);
        float4 o1 = make_float4(om[j] ? acc[j][4] : 0.f, om[j] ? acc[j][5] : 0.f,
                                om[j] ? acc[j][6] : 0.f, om[j] ? acc[j][7] : 0.f);
        ((float4*)op)[0] = o0;
        ((float4*)op)[1] = o1;
    }
}

// ================= 8^3 LDS-tiled kernels (16ch), quad-split + weights-in-LDS =================

// ---------------- conv k=3, 16->16, BN(affine+ReLU+mask) at stage-in ----------------
__global__ void convbn8_k(const float* __restrict__ in, const float* __restrict__ w,
                          const u8* __restrict__ mask, const double* __restrict__ params,
                          float* __restrict__ out) {
    __shared__ float4 til[4][330];   // 21.1 KB
    __shared__ float wl[27 * 256];   // 27 KB
    float sc[16], sh[16];
#pragma unroll
    for (int c = 0; c < 16; c++) { sc[c] = (float)params[c]; sh[c] = (float)params[16 + c]; }
    int z = blockIdx.x & 7, n = blockIdx.x >> 3;
    for (int t = threadIdx.x; t < 27 * 256; t += 256) wl[t] = w[t];
    for (int t = threadIdx.x; t < 300; t += 256) {
        int xx = t % 10;
        int rr = t / 10;
        int yy = rr % 10, zz = rr / 10;
        int gx = xx - 1, gy = yy - 1, gz = z + zz - 1;
        float v[16];
#pragma unroll
        for (int c = 0; c < 16; c++) v[c] = 0.f;
        if ((unsigned)gx < 8u && (unsigned)gy < 8u && (unsigned)gz < 8u) {
            int gi = ((n * 8 + gz) * 8 + gy) * 8 + gx;
            if (mask[gi]) {
                const float* ip = in + (size_t)gi * 16;
#pragma unroll
                for (int c = 0; c < 16; c++) v[c] = fmaxf(ip[c] * sc[c] + sh[c], 0.f);
            }
        }
        int s = (zz * 10 + yy) * 11 + xx;
#pragma unroll
        for (int q = 0; q < 4; q++)
            til[q][s] = make_float4(v[4 * q], v[4 * q + 1], v[4 * q + 2], v[4 * q + 3]);
    }
    __syncthreads();
    int x = threadIdx.x & 7, y = (threadIdx.x >> 3) & 7, cq = threadIdx.x >> 6;
    int v = ((n * 8 + z) * 8 + y) * 8 + x;
    u8 om = mask[v];
    float acc[4] = {0.f, 0.f, 0.f, 0.f};
    for (int kd = 0; kd < 3; kd++) {
        for (int kh = 0; kh < 3; kh++) {
            int rbase = (kd * 10 + y + kh) * 11 + x;
            const float* wrow = wl + ((kd * 3 + kh) * 3) * 256;
#pragma unroll
            for (int kw = 0; kw < 3; kw++) {
                int s = rbase + kw;
                float4 q0 = til[0][s], q1 = til[1][s], q2 = til[2][s], q3 = til[3][s];
                float xs[16] = {q0.x, q0.y, q0.z, q0.w, q1.x, q1.y, q1.z, q1.w,
                                q2.x, q2.y, q2.z, q2.w, q3.x, q3.y, q3.z, q3.w};
                const float* wt = wrow + kw * 256 + cq * 4;
#pragma unroll
                for (int ci = 0; ci < 16; ci++) {
                    float xv = xs[ci];
                    float4 w4 = *(const float4*)(wt + ci * 16);
                    acc[0] += xv * w4.x; acc[1] += xv * w4.y;
                    acc[2] += xv * w4.z; acc[3] += xv * w4.w;
                }
            }
        }
    }
    float4 o = make_float4(om ? acc[0] : 0.f, om ? acc[1] : 0.f,
                           om ? acc[2] : 0.f, om ? acc[3] : 0.f);
    *(float4*)(out + (size_t)v * 16 + cq * 4) = o;
}

// ---------------- conv k=3, 16->16 + fused sparsify (fp64 gate on wave 0) ----------------
__global__ void conv3s8_k(const float* __restrict__ in, const float* __restrict__ w,
                          const u8* __restrict__ pmask, u8* __restrict__ nmask,
                          float* __restrict__ out, double delta) {
    __shared__ float4 til[4][330];   // 21.1 KB
    __shared__ float wl[27 * 256];   // 27 KB
    __shared__ u8 nmsh[64];
    int z = blockIdx.x & 7, n = blockIdx.x >> 3;
    for (int t = threadIdx.x; t < 27 * 256; t += 256) wl[t] = w[t];
    for (int t = threadIdx.x; t < 300; t += 256) {
        int xx = t % 10;
        int rr = t / 10;
        int yy = rr % 10, zz = rr / 10;
        int gx = xx - 1, gy = yy - 1, gz = z + zz - 1;
        float4 v0 = make_float4(0.f, 0.f, 0.f, 0.f), v1 = v0, v2 = v0, v3 = v0;
        if ((unsigned)gx < 8u && (unsigned)gy < 8u && (unsigned)gz < 8u) {
            const float4* ip = (const float4*)(in + (size_t)(((n * 8 + gz) * 8 + gy) * 8 + gx) * 16);
            v0 = ip[0]; v1 = ip[1]; v2 = ip[2]; v3 = ip[3];
        }
        int s = (zz * 10 + yy) * 11 + xx;
        til[0][s] = v0; til[1][s] = v1; til[2][s] = v2; til[3][s] = v3;
    }
    __syncthreads();
    int x = threadIdx.x & 7, y = (threadIdx.x >> 3) & 7, cq = threadIdx.x >> 6;
    int v = ((n * 8 + z) * 8 + y) * 8 + x;
    double acc0 = 0.0, asum = 0.0;
    float acc[4] = {0.f, 0.f, 0.f, 0.f};
    for (int kd = 0; kd < 3; kd++) {
        for (int kh = 0; kh < 3; kh++) {
            int rbase = (kd * 10 + y + kh) * 11 + x;
            const float* wrow = wl + ((kd * 3 + kh) * 3) * 256;
#pragma unroll
            for (int kw = 0; kw < 3; kw++) {
                int s = rbase + kw;
                float4 q0 = til[0][s], q1 = til[1][s], q2 = til[2][s], q3 = til[3][s];
                float xs[16] = {q0.x, q0.y, q0.z, q0.w, q1.x, q1.y, q1.z, q1.w,
                                q2.x, q2.y, q2.z, q2.w, q3.x, q3.y, q3.z, q3.w};
                const float* wt0 = wrow + kw * 256;
                if (cq == 0) {   // wave-uniform branch: wave 0 carries the fp64 gate
#pragma unroll
                    for (int ci = 0; ci < 16; ci++) {
                        float xv = xs[ci];
                        double term = (double)xv * (double)wt0[ci * 16];
                        acc0 += term;
                        asum += fabs(term);
#pragma unroll
                        for (int j = 1; j < 4; j++) acc[j] += xv * wt0[ci * 16 + j];
                    }
                } else {
                    const float* wt = wt0 + cq * 4;
#pragma unroll
                    for (int ci = 0; ci < 16; ci++) {
                        float xv = xs[ci];
                        float4 w4 = *(const float4*)(wt + ci * 16);
                        acc[0] += xv * w4.x; acc[1] += xv * w4.y;
                        acc[2] += xv * w4.z; acc[3] += xv * w4.w;
                    }
                }
            }
        }
    }
    if (cq == 0) {
        u8 pm = pmask[((n * 4 + (z >> 1)) * 4 + (y >> 1)) * 4 + (x >> 1)];
        u8 nm = (pm && (acc0 > -delta * asum)) ? 1 : 0;
        nmsh[y * 8 + x] = nm;
        nmask[v] = nm;
    }
    __syncthreads();
    u8 nm = nmsh[y * 8 + x];
    float4 o;
    if (cq == 0) {
        o = make_float4(nm ? (float)acc0 : 0.f, nm ? acc[1] : 0.f,
                        nm ? acc[2] : 0.f, nm ? acc[3] : 0.f);
    } else {
        o = make_float4(nm ? acc[0] : 0.f, nm ? acc[1] : 0.f,
                        nm ? acc[2] : 0.f, nm ? acc[3] : 0.f);
    }
    *(float4*)(out + (size_t)v * 16 + cq * 4) = o;
}

// ---------------- plain conv k=4 pad(1,2), 16->16; weights staged per-kd slab ----------------
__global__ void conv48_k(const float* __restrict__ in, const float* __restrict__ w,
                         const u8* __restrict__ outmask, float* __restrict__ out) {
    __shared__ float4 til[4][572];   // 36.6 KB
    __shared__ float wl[16 * 256];   // 16 KB
    int z = blockIdx.x & 7, n = blockIdx.x >> 3;
    for (int t = threadIdx.x; t < 484; t += 256) {
        int xx = t % 11;
        int rr = t / 11;
        int yy = rr % 11, zz = rr / 11;
        int gx = xx - 1, gy = yy - 1, gz = z + zz - 1;
        float4 v0 = make_float4(0.f, 0.f, 0.f, 0.f), v1 = v0, v2 = v0, v3 = v0;
        if ((unsigned)gx < 8u && (unsigned)gy < 8u && (unsigned)gz < 8u) {
            const float4* ip = (const float4*)(in + (size_t)(((n * 8 + gz) * 8 + gy) * 8 + gx) * 16);
            v0 = ip[0]; v1 = ip[1]; v2 = ip[2]; v3 = ip[3];
        }
        int s = (zz * 11 + yy) * 13 + xx;
        til[0][s] = v0; til[1][s] = v1; til[2][s] = v2; til[3][s] = v3;
    }
    int x = threadIdx.x & 7, y = (threadIdx.x >> 3) & 7, cq = threadIdx.x >> 6;
    int v = ((n * 8 + z) * 8 + y) * 8 + x;
    u8 om = outmask[v];
    float acc[4] = {0.f, 0.f, 0.f, 0.f};
    for (int kd = 0; kd < 4; kd++) {
        __syncthreads();
        for (int t = threadIdx.x; t < 16 * 256; t += 256) wl[t] = w[kd * 16 * 256 + t];
        __syncthreads();
        for (int kh = 0; kh < 4; kh++) {
            int rbase = (kd * 11 + y + kh) * 13 + x;
            const float* wrow = wl + (kh * 4) * 256;
#pragma unroll
            for (int kw = 0; kw < 4; kw++) {
                int s = rbase + kw;
                float4 q0 = til[0][s], q1 = til[1][s], q2 = til[2][s], q3 = til[3][s];
                float xs[16] = {q0.x, q0.y, q0.z, q0.w, q1.x, q1.y, q1.z, q1.w,
                                q2.x, q2.y, q2.z, q2.w, q3.x, q3.y, q3.z, q3.w};
                const float* wt = wrow + kw * 256 + cq * 4;
#pragma unroll
                for (int ci = 0; ci < 16; ci++) {
                    float xv = xs[ci];
                    float4 w4 = *(const float4*)(wt + ci * 16);
                    acc[0] += xv * w4.x; acc[1] += xv * w4.y;
                    acc[2] += xv * w4.z; acc[3] += xv * w4.w;
                }
            }
        }
    }
    float4 o = make_float4(om ? acc[0] : 0.f, om ? acc[1] : 0.f,
                           om ? acc[2] : 0.f, om ? acc[3] : 0.f);
    *(float4*)(out + (size_t)v * 16 + cq * 4) = o;
}

// ================= remaining generic kernels =================

template <int CIN, int COUT, int SO>
__global__ void down_k(const float* __restrict__ in, const float* __restrict__ w,
                       const u8* __restrict__ outmask, float* __restrict__ out) {
    const int N = 128 * SO * SO * SO;
    constexpr int SI = 2 * SO;
    int v = blockIdx.x * blockDim.x + threadIdx.x;
    if (v >= N) return;
    if (!outmask[v]) {
#pragma unroll
        for (int co = 0; co < COUT; co++) out[(size_t)v * COUT + co] = 0.f;
        return;
    }
    int t = v;
    int x = t % SO; t /= SO;
    int y = t % SO; t /= SO;
    int z = t % SO;
    int n = t / SO;
    float acc[COUT];
#pragma unroll
    for (int co = 0; co < COUT; co++) acc[co] = 0.f;
    for (int kd = 0; kd < 2; kd++)
        for (int kh = 0; kh < 2; kh++)
            for (int kw = 0; kw < 2; kw++) {
                int sv = ((n * SI + 2 * z + kd) * SI + 2 * y + kh) * SI + 2 * x + kw;
                const float* ip = in + (size_t)sv * CIN;
                const float* wpk = w + ((kd * 2 + kh) * 2 + kw) * CIN * COUT;
#pragma unroll
                for (int ci = 0; ci < CIN; ci++) {
                    float xv = ip[ci];
#pragma unroll
                    for (int co = 0; co < COUT; co++) acc[co] += xv * wpk[ci * COUT + co];
                }
            }
#pragma unroll
    for (int co = 0; co < COUT; co++) out[(size_t)v * COUT + co] = acc[co];
}

template <int CIN, int COUT, int SI>
__global__ void upbn_k(const float* __restrict__ in, const float* __restrict__ w,
                       const u8* __restrict__ inmask, const double* __restrict__ params,
                       float* __restrict__ out) {
    constexpr int SO = 2 * SI;
    const int N = 128 * SO * SO * SO;
    int v = blockIdx.x * blockDim.x + threadIdx.x;
    if (v >= N) return;
    int t = v;
    int x = t % SO; t /= SO;
    int y = t % SO; t /= SO;
    int z = t % SO;
    int n = t / SO;
    int sv = ((n * SI + (z >> 1)) * SI + (y >> 1)) * SI + (x >> 1);
    if (!inmask[sv]) {
#pragma unroll
        for (int co = 0; co < COUT; co++) out[(size_t)v * COUT + co] = 0.f;
        return;
    }
    int tap = ((1 - (z & 1)) * 2 + (1 - (y & 1))) * 2 + (1 - (x & 1));
    const float* wpk = w + tap * CIN * COUT;
    const float* ip = in + (size_t)sv * CIN;
    float acc[COUT];
#pragma unroll
    for (int co = 0; co < COUT; co++) acc[co] = 0.f;
#pragma unroll
    for (int ci = 0; ci < CIN; ci++) {
        float yv = fmaxf(ip[ci] * (float)params[ci] + (float)params[CIN + ci], 0.f);
#pragma unroll
        for (int co = 0; co < COUT; co++) acc[co] += yv * wpk[ci * COUT + co];
    }
#pragma unroll
    for (int co = 0; co < COUT; co++) out[(size_t)v * COUT + co] = acc[co];
}

// ---------------- BN masked reduce, DETERMINISTIC two-pass: per-block partials ----------------
template <int C>
__global__ void bn_reduce_k(const float* __restrict__ x, const u8* __restrict__ m, int N,
                            double* __restrict__ partial) {
    double cnt = 0.0, sx[C], s2[C];
#pragma unroll
    for (int c = 0; c < C; c++) { sx[c] = 0.0; s2[c] = 0.0; }
    int stride = gridDim.x * blockDim.x;
    for (int v = blockIdx.x * blockDim.x + threadIdx.x; v < N; v += stride) {
        float mk = (float)m[v];
        cnt += (double)mk;
        const float4* xp = (const float4*)(x + (size_t)v * C);
#pragma unroll
        for (int q = 0; q < C / 4; q++) {
            float4 r = xp[q];
            float f0 = r.x * mk, f1 = r.y * mk, f2 = r.z * mk, f3 = r.w * mk;
            double x0 = (double)f0, x1 = (double)f1, x2 = (double)f2, x3 = (double)f3;
            sx[4 * q + 0] += x0; s2[4 * q + 0] += x0 * x0;
            sx[4 * q + 1] += x1; s2[4 * q + 1] += x1 * x1;
            sx[4 * q + 2] += x2; s2[4 * q + 2] += x2 * x2;
            sx[4 * q + 3] += x3; s2[4 * q + 3] += x3 * x3;
        }
    }
#pragma unroll
    for (int off = 32; off > 0; off >>= 1) {
        cnt += __shfl_down(cnt, off, 64);
#pragma unroll
        for (int c = 0; c < C; c++) {
            sx[c] += __shfl_down(sx[c], off, 64);
            s2[c] += __shfl_down(s2[c], off, 64);
        }
    }
    __shared__ double sbuf[4][2 * C + 1];
    int wave = threadIdx.x >> 6;
    if ((threadIdx.x & 63) == 0) {
        sbuf[wave][0] = cnt;
#pragma unroll
        for (int c = 0; c < C; c++) {
            sbuf[wave][1 + c] = sx[c];
            sbuf[wave][1 + C + c] = s2[c];
        }
    }
    __syncthreads();
    if (threadIdx.x == 0) {
        double* p = partial + (size_t)blockIdx.x * (2 * C + 1);
        double tcnt = 0.0;
        for (int wv = 0; wv < 4; wv++) tcnt += sbuf[wv][0];
        p[0] = tcnt;
#pragma unroll
        for (int c = 0; c < C; c++) {
            double a = 0.0, b = 0.0;
            for (int wv = 0; wv < 4; wv++) { a += sbuf[wv][1 + c]; b += sbuf[wv][1 + C + c]; }
            p[1 + c] = a;
            p[1 + C + c] = b;
        }
    }
}

// ---------------- BN finalize: fixed-order sum of block partials ----------------
template <int C>
__global__ void bn_final_k(const double* __restrict__ partial, int nblocks,
                           const float* __restrict__ g, const float* __restrict__ b,
                           double* __restrict__ params) {
    int c = threadIdx.x;
    if (c >= C) return;
    double cnt = 0.0, sx = 0.0, s2 = 0.0;
    for (int bk = 0; bk < nblocks; bk++) {
        const double* p = partial + (size_t)bk * (2 * C + 1);
        cnt += p[0];
        sx += p[1 + c];
        s2 += p[1 + C + c];
    }
    if (cnt < 1.0) cnt = 1.0;
    double mean = sx / cnt;
    double var = s2 / cnt - mean * mean;
    double sc = (double)g[c] / sqrt(var + 1e-4);
    params[c] = sc;
    params[C + c] = (double)b[c] - mean * sc;
}

// ---------------- hidden: NDHWC (4^3, 32ch) -> NCDHW flat ----------------
__global__ void hidden_k(const float* __restrict__ x, float* __restrict__ out) {
    int i = blockIdx.x * blockDim.x + threadIdx.x;
    if (i >= 128 * 2048) return;
    int b = i >> 11;
    int r = i & 2047;
    int c = r >> 6;
    int s = r & 63;
    int d = s >> 4;
    int h = (s >> 2) & 3;
    int w = s & 3;
    out[i] = x[((((b * 4 + d) * 4 + h) * 4 + w) << 5) + c];
}

extern "C" void kernel_launch(void* const* d_in, const int* in_sizes, int n_in,
                              void* d_out, int out_size, void* d_ws, size_t ws_size,
                              hipStream_t stream) {
    const float* vox = (const float*)d_in[0];
    const int* mraw = (const int*)d_in[1];
    const float* wp = (const float*)d_in[2];
    const float* g_e0 = (const float*)d_in[3];
    const float* b_e0 = (const float*)d_in[4];
    const float* ws_e0 = (const float*)d_in[5];
    const float* wd_e0 = (const float*)d_in[6];
    const float* g_e1 = (const float*)d_in[7];
    const float* b_e1 = (const float*)d_in[8];
    const float* ws_e1 = (const float*)d_in[9];
    const float* wd_e1 = (const float*)d_in[10];
    const float* g_e2 = (const float*)d_in[11];
    const float* b_e2 = (const float*)d_in[12];
    const float* ws_e2 = (const float*)d_in[13];
    const float* wd_e2 = (const float*)d_in[14];
    const float* g_d0 = (const float*)d_in[15];
    const float* b_d0 = (const float*)d_in[16];
    const float* wu_d0 = (const float*)d_in[17];
    const float* ws3_d0 = (const float*)d_in[18];
    const float* ws4_d0 = (const float*)d_in[19];
    const float* g_d1 = (const float*)d_in[20];
    const float* b_d1 = (const float*)d_in[21];
    const float* wu_d1 = (const float*)d_in[22];
    const float* ws3_d1 = (const float*)d_in[23];
    const float* ws4_d1 = (const float*)d_in[24];
    const float* g_d2 = (const float*)d_in[25];
    const float* b_d2 = (const float*)d_in[26];
    const float* wu_d2 = (const float*)d_in[27];
    const float* ws3_d2 = (const float*)d_in[28];
    const float* ws4_d2 = (const float*)d_in[29];
    const float* wo = (const float*)d_in[30];
    float* out = (float*)d_out;

    // ---- workspace: fp32 tensors + fp64 partials/params + u8 masks (~153 MB) ----
    float* wsf = (float*)d_ws;
    size_t offf = 0;
    auto allocf = [&](size_t n) { float* p = wsf + offf; offf += n; return p; };
    float* R1 = allocf(16777216);
    float* R2 = allocf(16777216);
    float* S1 = allocf(1048576);
    float* S2 = allocf(1048576);
    float* T = allocf(262144);
    double* wsd = (double*)(wsf + offf);
    double* partial = wsd;          // up to 256 blocks x (2*32+1) doubles
    double* params = wsd + 16640;
    u8* wsm = (u8*)(wsd + 16640 + 128);
    size_t offm = 0;
    auto allocm = [&](size_t n) { u8* p = wsm + offm; offm += n; return p; };
    u8* m32 = allocm(4194304);
    u8* m16 = allocm(524288);
    u8* m8 = allocm(65536);
    u8* m4 = allocm(8192);
    u8* mD8 = allocm(65536);
    u8* mD16 = allocm(524288);
    u8* mD32 = allocm(4194304);

    const int N32 = 128 * 32768;
    const int N16 = 128 * 4096;
    const int N8 = 128 * 512;
    const int N4 = 128 * 64;
    auto gs = [](int n) { return dim3((n + 255) / 256); };
    auto rbn = [](int n) { int bl = (n + 255) / 256; return bl > 256 ? 256 : bl; };
    dim3 blk(256);
    dim3 tgrid(4096);               // 32^3: 128 images x 4 y-tiles x 8 z-tiles
    dim3 grid16(1024);              // 16^3: 128 images x 2 y-tiles x 4 z-tiles
    dim3 grid8(1024);               // 8^3: 128 images x 8 z-planes

    // masks
    mask_init_k<<<gs(N32), blk, 0, stream>>>(mraw, m32, N32);
    pool_k<16><<<gs(N16), blk, 0, stream>>>(m32, m16);
    pool_k<8><<<gs(N8), blk, 0, stream>>>(m16, m8);
    pool_k<4><<<gs(N4), blk, 0, stream>>>(m8, m4);

    // ---- encoder stage 0 @32^3, LDS-tiled dense ----
    prep4t_k<<<tgrid, blk, 0, stream>>>(vox, m32, wp, R1);
    int nb0 = rbn(N32);
    bn_reduce_k<4><<<dim3(nb0), blk, 0, stream>>>(R1, m32, N32, partial);
    bn_final_k<4><<<1, 64, 0, stream>>>(partial, nb0, g_e0, b_e0, params);
    convbn4t_k<<<tgrid, blk, 0, stream>>>(R1, ws_e0, m32, params, R2);
    down_k<4, 8, 16><<<gs(N16), blk, 0, stream>>>(R2, wd_e0, m16, R1);

    // ---- encoder stage 1 @16^3, LDS-tiled ----
    int nb1 = rbn(N16);
    bn_reduce_k<8><<<dim3(nb1), blk, 0, stream>>>(R1, m16, N16, partial);
    bn_final_k<8><<<1, 64, 0, stream>>>(partial, nb1, g_e1, b_e1, params);
    convbn16t_k<<<grid16, blk, 0, stream>>>(R1, ws_e1, m16, params, R2);
    down_k<8, 16, 8><<<gs(N8), blk, 0, stream>>>(R2, wd_e1, m8, S1);

    // ---- encoder stage 2 @8^3, quad-split LDS-tiled + weights-in-LDS ----
    int nb2 = rbn(N8);
    bn_reduce_k<16><<<dim3(nb2), blk, 0, stream>>>(S1, m8, N8, partial);
    bn_final_k<16><<<1, 64, 0, stream>>>(partial, nb2, g_e2, b_e2, params);
    convbn8_k<<<grid8, blk, 0, stream>>>(S1, ws_e2, m8, params, S2);
    down_k<16, 32, 4><<<gs(N4), blk, 0, stream>>>(S2, wd_e2, m4, T);

    // ---- hidden ----
    hidden_k<<<gs(128 * 2048), blk, 0, stream>>>(T, out);

    // ---- decoder stage 0 (32->16, 4^3 -> 8^3), band gate delta=4e-7 ----
    int nb3 = rbn(N4);
    bn_reduce_k<32><<<dim3(nb3), blk, 0, stream>>>(T, m4, N4, partial);
    bn_final_k<32><<<1, 64, 0, stream>>>(partial, nb3, g_d0, b_d0, params);
    upbn_k<32, 16, 4><<<gs(N8), blk, 0, stream>>>(T, wu_d0, m4, params, S1);
    conv3s8_k<<<grid8, blk, 0, stream>>>(S1, ws3_d0, m4, mD8, S2, 4e-7);
    conv48_k<<<grid8, blk, 0, stream>>>(S2, ws4_d0, mD8, S1);

    // ---- decoder stage 1 (16->8, 8^3 -> 16^3), band gate delta=4e-7, LDS-tiled ----
    int nb4 = rbn(N8);
    bn_reduce_k<16><<<dim3(nb4), blk, 0, stream>>>(S1, mD8, N8, partial);
    bn_final_k<16><<<1, 64, 0, stream>>>(partial, nb4, g_d1, b_d1, params);
    upbn_k<16, 8, 8><<<gs(N16), blk, 0, stream>>>(S1, wu_d1, mD8, params, R1);
    conv3s16t_k<<<grid16, blk, 0, stream>>>(R1, ws3_d1, mD8, mD16, R2, 4e-7);
    conv416t_k<<<grid16, blk, 0, stream>>>(R2, ws4_d1, mD16, R1);

    // ---- decoder stage 2 (8->4, 16^3 -> 32^3), exact gate, LDS-tiled dense ----
    int nb5 = rbn(N16);
    bn_reduce_k<8><<<dim3(nb5), blk, 0, stream>>>(R1, mD16, N16, partial);
    bn_final_k<8><<<1, 64, 0, stream>>>(partial, nb5, g_d2, b_d2, params);
    upbn_k<8, 4, 16><<<gs(N32), blk, 0, stream>>>(R1, wu_d2, mD16, params, R2);
    conv3s4t_k<<<tgrid, blk, 0, stream>>>(R2, ws3_d2, mD16, mD32, R1);
    conv4x4t_k<<<tgrid, blk, 0, stream>>>(R1, ws4_d2, mD32, R2);
    outconv4t_k<<<tgrid, blk, 0, stream>>>(R2, wo, mD32, out + 262144);
}